// Round 5
// baseline (1215.652 us; speedup 1.0000x reference)
//
#include <hip/hip_runtime.h>
#include <stdint.h>

#define B_ 4
#define T_ 2048
#define D_ 1024
#define N_ 1024
#define TC 32
#define NCH (T_/TC)
#define SQN 8   // squaring GEMMs after gram; +1 effective doubling via fused Frobenius

typedef __attribute__((ext_vector_type(4))) float f32x4;
typedef __attribute__((ext_vector_type(8))) short bf16x8;
typedef __attribute__((ext_vector_type(4))) unsigned short us4;

__device__ __forceinline__ unsigned short f2bf(float f){
  unsigned int u = __float_as_uint(f);
  return (unsigned short)((u + 0x7fffu + ((u >> 16) & 1u)) >> 16);
}
__device__ __forceinline__ float bf2f(unsigned short h){
  return __uint_as_float(((unsigned int)h) << 16);
}

// ---- device-scope grid barrier (all blocks co-resident by capacity arithmetic) ----
__device__ __forceinline__ void gsync(unsigned* bar, unsigned target){
  __syncthreads();                       // drains each wave's vmcnt -> all stores/atomics done
  if (threadIdx.x == 0){
    __threadfence();                     // device-scope release
    atomicAdd(bar, 1u);
    while (__hip_atomic_load(bar, __ATOMIC_ACQUIRE, __HIP_MEMORY_SCOPE_AGENT) < target)
      __builtin_amdgcn_s_sleep(2);
    __threadfence();                     // device-scope acquire (invalidate local caches)
  }
  __syncthreads();
}

// ---- fused fp32->bf16 conversion of all inputs + sc/barrier zero-init ----
#define U4    2097152   // 8192*1024/4
#define WIN4   262144   // 1024*1024/4
#define PNW4   786432   // 3072*1024/4
#define WOUT4  262144
#define CONV_BLOCKS ((U4 + WIN4 + PNW4 + WOUT4 + 255)/256)

__global__ void k_convert_all(const float* __restrict__ u, const float* __restrict__ Win,
                              const float* __restrict__ pnw, const float* __restrict__ Wout,
                              unsigned short* __restrict__ u16, unsigned short* __restrict__ Wcat16,
                              unsigned short* __restrict__ Wout16, float* __restrict__ sc){
  if (blockIdx.x == 0 && threadIdx.x < 128) sc[threadIdx.x] = 0.f;   // traces + barrier counters
  long i = (long)blockIdx.x * 256 + threadIdx.x;   // float4 index
  const float* src; unsigned short* dst; long o;
  if (i < U4)                      { src = u;    dst = u16;               o = i; }
  else if (i < U4+WIN4)            { src = Win;  dst = Wcat16;            o = i - U4; }
  else if (i < U4+WIN4+PNW4)       { src = pnw;  dst = Wcat16 + 1048576;  o = i - (U4+WIN4); }
  else if (i < U4+WIN4+PNW4+WOUT4) { src = Wout; dst = Wout16;            o = i - (U4+WIN4+PNW4); }
  else return;
  float4 v = ((const float4*)src)[o];
  us4 w;
  w.x = f2bf(v.x); w.y = f2bf(v.y); w.z = f2bf(v.z); w.w = f2bf(v.w);
  ((us4*)dst)[o] = w;
}

__device__ __forceinline__ void load_lds16(const unsigned short* g, unsigned short* l){
  __builtin_amdgcn_global_load_lds((const __attribute__((address_space(1))) void*)g,
                                   (__attribute__((address_space(3))) void*)l, 16, 0, 0);
}

// ---- big GEMM: C[M,N] = (A[M,K] * B[N,K]^T), bf16 out (128x128 tile, proven m97-structure) ----
template<int OUTBF16>
__global__ __launch_bounds__(256) void k_gemm(
    const unsigned short* __restrict__ A,
    const unsigned short* __restrict__ Bmat,
    void* __restrict__ C0,
    int M, int N, int K,
    const float* __restrict__ sc, int step)
{
  __shared__ alignas(16) unsigned short As[128*64];
  __shared__ alignas(16) unsigned short Bs[128*64];
  const int tid = threadIdx.x;
  const int wid = tid >> 6;
  const int lane = tid & 63;
  const int bn = blockIdx.x, bm = blockIdx.y;

  char* C = (char*)C0;
  float outscale = (step >= 0) ? sc[step] : 1.f;

  const int wr = wid >> 1, wc = wid & 1;
  const int rg = lane >> 3;
  const int cby = (lane & 7) << 4;
  const int srow0 = wid * 32;
  const int frow = lane & 15;
  const int kgrp = lane >> 4;

  const size_t Abase = (size_t)bm * 128 * K;
  const size_t Bbase = (size_t)bn * 128 * K;

  f32x4 acc[4][4] = {};

  for (int kt = 0; kt < K; kt += 64){
    #pragma unroll
    for (int i = 0; i < 4; i++){
      int r = srow0 + i*8 + rg;
      int cb = cby ^ ((r & 7) << 4);
      load_lds16(A    + Abase + (size_t)r*K + kt + (cb >> 1), As + (srow0 + i*8)*64);
      load_lds16(Bmat + Bbase + (size_t)r*K + kt + (cb >> 1), Bs + (srow0 + i*8)*64);
    }
    __syncthreads();
    #pragma unroll
    for (int kk = 0; kk < 2; kk++){
      const int kbyte = kk*64 + kgrp*16;
      bf16x8 af[4], bfv[4];
      #pragma unroll
      for (int m = 0; m < 4; m++){
        int r = wr*64 + m*16 + frow;
        af[m] = *(const bf16x8*)((const char*)As + r*128 + (kbyte ^ ((r & 7) << 4)));
      }
      #pragma unroll
      for (int n2 = 0; n2 < 4; n2++){
        int r = wc*64 + n2*16 + frow;
        bfv[n2] = *(const bf16x8*)((const char*)Bs + r*128 + (kbyte ^ ((r & 7) << 4)));
      }
      #pragma unroll
      for (int m = 0; m < 4; m++)
        #pragma unroll
        for (int n2 = 0; n2 < 4; n2++)
          acc[m][n2] = __builtin_amdgcn_mfma_f32_16x16x32_bf16(af[m], bfv[n2], acc[m][n2], 0, 0, 0);
    }
    __syncthreads();
  }

  const int row0 = bm*128 + wr*64;
  const int col0 = bn*128 + wc*64 + frow;
  #pragma unroll
  for (int m = 0; m < 4; m++){
    #pragma unroll
    for (int n2 = 0; n2 < 4; n2++){
      const int col = col0 + n2*16;
      const int rb = row0 + m*16 + kgrp*4;
      #pragma unroll
      for (int j = 0; j < 4; j++){
        float v = acc[m][n2][j] * outscale;
        if (OUTBF16) ((unsigned short*)C)[(size_t)(rb + j)*N + col] = f2bf(v);
        else         ((float*)C)[(size_t)(rb + j)*N + col] = v;
      }
    }
  }
}

// ---- persistent spectral-norm chain: gram + SQN trace-normalized squarings + frob + final ----
// 512 blocks (2/CU by 64KB LDS -> capacity 512 = grid, co-resident). One grid barrier per step.
__global__ __launch_bounds__(256) void k_chain(
    const unsigned short* __restrict__ W0,   // W_in (top of Wcat16)
    const unsigned short* __restrict__ W1,   // W_out
    unsigned short* __restrict__ Hp,         // ping (2 matrices)
    unsigned short* __restrict__ Hq,         // pong (2 matrices)
    float* sc, unsigned* bar)
{
  __shared__ alignas(16) unsigned short As0[64*128], Bs0[64*128];
  __shared__ alignas(16) unsigned short As1[64*128], Bs1[64*128];
  const int tid = threadIdx.x;
  const int wid = tid >> 6;
  const int lane = tid & 63;
  const int bid = blockIdx.x;
  const int z  = bid >> 8;
  const int bm = (bid >> 4) & 15, bn = bid & 15;
  const size_t M2 = (size_t)1024*1024;

  const int wr = wid >> 1, wc = wid & 1;     // 32x32 quadrant per wave
  const int frow = lane & 15;
  const int kgrp = lane >> 4;
  const int srl = lane >> 4;
  const int sgr = lane & 15;
  const int swzr = wid*4 + srl;
  const int scol_e = ((sgr ^ swzr) << 3);
  const size_t Arow = (size_t)bm * 64;
  const size_t Brow = (size_t)bn * 64;

  for (int step = 0; step <= SQN; step++){
    const unsigned short* A = (step == 0) ? (z ? W1 : W0)
                             : (((step & 1) ? Hp : Hq) + (z ? M2 : 0));
    unsigned short* C = ((step & 1) ? Hq : Hp) + (z ? M2 : 0);
    float outscale = 1.f;
    if (step > 0){
      float t = __hip_atomic_load(&sc[8 + (step-1)*2 + z], __ATOMIC_ACQUIRE, __HIP_MEMORY_SCOPE_AGENT);
      outscale = 1.f / (t*t);
    }

    f32x4 acc[2][2] = {};

    auto stage = [&](unsigned short* as, unsigned short* bs, int t2){
      const int kt = t2 * 128;
      #pragma unroll
      for (int i = 0; i < 4; i++){
        int r = i*16 + wid*4 + srl;
        load_lds16(A + (Arow + r)*1024 + kt + scol_e, as + (i*16 + wid*4)*128);
        load_lds16(A + (Brow + r)*1024 + kt + scol_e, bs + (i*16 + wid*4)*128);
      }
    };
    auto compute = [&](const unsigned short* as, const unsigned short* bs){
      #pragma unroll
      for (int ks = 0; ks < 4; ks++){
        const int kb = ks*64 + kgrp*16;
        bf16x8 af[2], bfv[2];
        #pragma unroll
        for (int m = 0; m < 2; m++){
          int r = wr*32 + m*16 + frow;
          af[m] = *(const bf16x8*)((const char*)as + r*256 + (kb ^ (frow << 4)));
        }
        #pragma unroll
        for (int n2 = 0; n2 < 2; n2++){
          int r = wc*32 + n2*16 + frow;
          bfv[n2] = *(const bf16x8*)((const char*)bs + r*256 + (kb ^ (frow << 4)));
        }
        #pragma unroll
        for (int m = 0; m < 2; m++)
          #pragma unroll
          for (int n2 = 0; n2 < 2; n2++)
            acc[m][n2] = __builtin_amdgcn_mfma_f32_16x16x32_bf16(af[m], bfv[n2], acc[m][n2], 0, 0, 0);
      }
    };

    stage(As0, Bs0, 0);
    __syncthreads();
    for (int t2 = 0; t2 < 8; t2 += 2){
      if (t2 + 1 < 8) stage(As1, Bs1, t2 + 1);
      compute(As0, Bs0);
      __syncthreads();
      if (t2 + 2 < 8) stage(As0, Bs0, t2 + 2);
      compute(As1, Bs1);
      __syncthreads();
    }

    const int row0 = bm*64 + wr*32;
    const int col0 = bn*64 + wc*32 + frow;
    float fr = 0.f;
    #pragma unroll
    for (int m = 0; m < 2; m++){
      #pragma unroll
      for (int n2 = 0; n2 < 2; n2++){
        const int col = col0 + n2*16;
        const int rb = row0 + m*16 + kgrp*4;
        #pragma unroll
        for (int j = 0; j < 4; j++){
          float v = acc[m][n2][j] * outscale;
          C[(size_t)(rb + j)*1024 + col] = f2bf(v);
          fr += v*v;
        }
      }
    }
    if (bm == bn && wr == wc){
      int j = frow - kgrp*4;
      if (j >= 0 && j < 4){
        float d = (acc[0][0][j] + acc[1][1][j]) * outscale;
        atomicAdd(&sc[8 + step*2 + z], d);
      }
    }
    if (step == SQN){
      #pragma unroll
      for (int off = 32; off; off >>= 1) fr += __shfl_down(fr, off, 64);
      if (lane == 0) atomicAdd(&sc[8 + 2*(SQN+1) + z], fr);
    }
    gsync(bar, (unsigned)((step + 1) * 512));
  }

  // fused final: sc[z] = 1/max(sigma,1)
  if (bid == 0 && tid < 2){
    const int zz = tid;
    float ll = 0.f, w = 1.f, t = 1.f;
    for (int i = 0; i <= SQN; i++){
      t = __hip_atomic_load(&sc[8 + 2*i + zz], __ATOMIC_RELAXED, __HIP_MEMORY_SCOPE_AGENT);
      ll += w * __logf(t);
      w *= 0.5f;
    }
    float F = __hip_atomic_load(&sc[8 + 2*(SQN+1) + zz], __ATOMIC_RELAXED, __HIP_MEMORY_SCOPE_AGENT);
    ll += w * __logf(F / (t*t));
    float sig = __expf(0.5f * ll);
    sig = fmaxf(sig, 1e-5f);
    sc[zz] = 1.f / fmaxf(sig, 1.f);
  }
}

__device__ __forceinline__ float softplusf(float x){
  return (x > 0.f) ? (x + __logf(1.f + __expf(-x))) : __logf(1.f + __expf(x));
}
__device__ __forceinline__ float tanhfastf(float x){
  float e = __expf(2.f * x);
  return 1.f - 2.f/(e + 1.f);
}
__device__ __forceinline__ void abc_from(float pin, float draw, float braw, float craw,
    float alpha, float ginv, float& a_o, float& bu_o, float& c_o){
  float sp = softplusf(draw);
  float av = __expf(-sp * alpha);
  av = fminf(av, 1.f - 1e-4f);
  float bv = tanhfastf(braw);
  float cv = tanhfastf(craw);
  float p = av*av + cv*cv;
  float r = bv*bv;
  float q = av*bv;
  float pr = p - r;
  float disc = pr*pr + 4.f*q*q;
  float lam = 0.5f*(p + r + sqrtf(disc + 1e-12f));
  float sig = sqrtf(lam + 1e-12f);
  float inv = 1.f / fmaxf(sig, 1.f);
  a_o = av * inv;
  c_o = cv * inv;
  bu_o = (bv * inv) * (pin * ginv);
}

// ---- fused tail: pass1 | pass2 | pass3 | out-GEMM, 512 blocks, 3 grid barriers ----
__global__ __launch_bounds__(256) void k_tail(
    const unsigned short* __restrict__ P,
    const float* __restrict__ alog, const float* __restrict__ dbias,
    const float* __restrict__ pnb, const float* __restrict__ lgam,
    const float* __restrict__ sc, const float* __restrict__ z0,
    float* __restrict__ Asum, float* __restrict__ Ssum, float* __restrict__ Zent,
    unsigned short* __restrict__ yh,
    const unsigned short* __restrict__ Wout16, float* __restrict__ dout,
    unsigned* bar)
{
  __shared__ alignas(16) unsigned short As[128*64];
  __shared__ alignas(16) unsigned short Bs[128*64];
  const int tid = threadIdx.x;
  const int bid = blockIdx.x;

  // role decomposition for phases 1 & 3 (was grid (64,2,4))
  const int ch = bid & 63, ny = (bid >> 6) & 1, pb = bid >> 7;
  const int n0 = ny*512 + tid*2;
  const float ginv = __expf(lgam[0]) * sc[0];
  float alpha[2], bd[2], bb[2], bc[2];
  #pragma unroll
  for (int j = 0; j < 2; j++){
    alpha[j] = softplusf(alog[n0+j]);
    bd[j] = dbias[n0+j] + pnb[n0+j];
    bb[j] = pnb[N_ + n0+j];
    bc[j] = pnb[2*N_ + n0+j];
  }

  // ---- phase 1: per-chunk (A,S) ----
  {
    float A[2] = {1.f, 1.f}, S[2] = {0.f, 0.f};
    const unsigned short* Pr = P + (size_t)(pb*T_ + ch*TC) * (4*N_);
    #pragma unroll 4
    for (int i = 0; i < TC; i++){
      unsigned int vp = *(const unsigned int*)(Pr + n0);
      unsigned int vd = *(const unsigned int*)(Pr + N_ + n0);
      unsigned int vb = *(const unsigned int*)(Pr + 2*N_ + n0);
      unsigned int vc = *(const unsigned int*)(Pr + 3*N_ + n0);
      #pragma unroll
      for (int j = 0; j < 2; j++){
        float pin  = bf2f((unsigned short)(j ? (vp>>16) : (vp & 0xffffu)));
        float draw = bf2f((unsigned short)(j ? (vd>>16) : (vd & 0xffffu))) + bd[j];
        float braw = bf2f((unsigned short)(j ? (vb>>16) : (vb & 0xffffu))) + bb[j];
        float craw = bf2f((unsigned short)(j ? (vc>>16) : (vc & 0xffffu))) + bc[j];
        float a, bu, c;
        abc_from(pin, draw, braw, craw, alpha[j], ginv, a, bu, c);
        S[j] = fmaf(a, S[j], bu);
        A[j] *= a;
      }
      Pr += 4*N_;
    }
    const size_t idx = (size_t)(pb*NCH + ch)*N_ + n0;
    Asum[idx] = A[0]; Asum[idx+1] = A[1];
    Ssum[idx] = S[0]; Ssum[idx+1] = S[1];
  }
  gsync(bar, 512u);

  // ---- phase 2: chunk-boundary scan (16 active blocks) ----
  if (bid < 16){
    const int n = (bid & 3)*256 + tid;
    const int b2 = bid >> 2;
    float zv = z0[b2*N_ + n];
    for (int c2 = 0; c2 < NCH; c2++){
      const size_t idx = (size_t)(b2*NCH + c2)*N_ + n;
      Zent[idx] = zv;
      zv = fmaf(Asum[idx], zv, Ssum[idx]);
    }
  }
  gsync(bar, 1024u);

  // ---- phase 3: recompute gates, emit y_hat = c * z(before) ----
  {
    float zr[2];
    const size_t zidx = (size_t)(pb*NCH + ch)*N_ + n0;
    zr[0] = Zent[zidx]; zr[1] = Zent[zidx+1];
    const unsigned short* Pr = P + (size_t)(pb*T_ + ch*TC) * (4*N_);
    unsigned short* Y = yh + (size_t)(pb*T_ + ch*TC)*N_ + n0;
    #pragma unroll 4
    for (int i = 0; i < TC; i++){
      unsigned int vp = *(const unsigned int*)(Pr + n0);
      unsigned int vd = *(const unsigned int*)(Pr + N_ + n0);
      unsigned int vb = *(const unsigned int*)(Pr + 2*N_ + n0);
      unsigned int vc = *(const unsigned int*)(Pr + 3*N_ + n0);
      unsigned int ow = 0;
      #pragma unroll
      for (int j = 0; j < 2; j++){
        float pin  = bf2f((unsigned short)(j ? (vp>>16) : (vp & 0xffffu)));
        float draw = bf2f((unsigned short)(j ? (vd>>16) : (vd & 0xffffu))) + bd[j];
        float braw = bf2f((unsigned short)(j ? (vb>>16) : (vb & 0xffffu))) + bb[j];
        float craw = bf2f((unsigned short)(j ? (vc>>16) : (vc & 0xffffu))) + bc[j];
        float a, bu, c;
        abc_from(pin, draw, braw, craw, alpha[j], ginv, a, bu, c);
        float yv = c * zr[j];
        zr[j] = fmaf(a, zr[j], bu);
        ow |= ((unsigned int)f2bf(yv)) << (16*j);
      }
      *(unsigned int*)Y = ow;
      Y += N_;
      Pr += 4*N_;
    }
  }
  gsync(bar, 1536u);

  // ---- phase 4: y = (y_hat @ W_out^T) * sc[1], fp32 out (128^2 tile, was grid (8,64)) ----
  {
    const int bn = bid & 7, bm = bid >> 3;
    const int wid = tid >> 6;
    const int lane = tid & 63;
    const float outscale = sc[1];
    const int wr = wid >> 1, wc = wid & 1;
    const int rg = lane >> 3;
    const int cby = (lane & 7) << 4;
    const int srow0 = wid * 32;
    const int frow = lane & 15;
    const int kgrp = lane >> 4;
    const size_t Abase = (size_t)bm * 128 * 1024;
    const size_t Bbase = (size_t)bn * 128 * 1024;

    f32x4 acc[4][4] = {};

    for (int kt = 0; kt < 1024; kt += 64){
      #pragma unroll
      for (int i = 0; i < 4; i++){
        int r = srow0 + i*8 + rg;
        int cb = cby ^ ((r & 7) << 4);
        load_lds16(yh     + Abase + (size_t)r*1024 + kt + (cb >> 1), As + (srow0 + i*8)*64);
        load_lds16(Wout16 + Bbase + (size_t)r*1024 + kt + (cb >> 1), Bs + (srow0 + i*8)*64);
      }
      __syncthreads();
      #pragma unroll
      for (int kk = 0; kk < 2; kk++){
        const int kbyte = kk*64 + kgrp*16;
        bf16x8 af[4], bfv[4];
        #pragma unroll
        for (int m = 0; m < 4; m++){
          int r = wr*64 + m*16 + frow;
          af[m] = *(const bf16x8*)((const char*)As + r*128 + (kbyte ^ ((r & 7) << 4)));
        }
        #pragma unroll
        for (int n2 = 0; n2 < 4; n2++){
          int r = wc*64 + n2*16 + frow;
          bfv[n2] = *(const bf16x8*)((const char*)Bs + r*128 + (kbyte ^ ((r & 7) << 4)));
        }
        #pragma unroll
        for (int m = 0; m < 4; m++)
          #pragma unroll
          for (int n2 = 0; n2 < 4; n2++)
            acc[m][n2] = __builtin_amdgcn_mfma_f32_16x16x32_bf16(af[m], bfv[n2], acc[m][n2], 0, 0, 0);
      }
      __syncthreads();
    }

    const int row0 = bm*128 + wr*64;
    const int col0 = bn*128 + wc*64 + frow;
    #pragma unroll
    for (int m = 0; m < 4; m++){
      #pragma unroll
      for (int n2 = 0; n2 < 4; n2++){
        const int col = col0 + n2*16;
        const int rb = row0 + m*16 + kgrp*4;
        #pragma unroll
        for (int j = 0; j < 4; j++)
          dout[(size_t)(rb + j)*1024 + col] = acc[m][n2][j] * outscale;
      }
    }
  }
}

extern "C" void kernel_launch(void* const* d_in, const int* in_sizes, int n_in,
                              void* d_out, int out_size, void* d_ws, size_t ws_size,
                              hipStream_t stream)
{
  const float* u    = (const float*)d_in[0];
  const float* z0   = (const float*)d_in[1];
  const float* Win  = (const float*)d_in[2];
  const float* Wout = (const float*)d_in[3];
  const float* pnw  = (const float*)d_in[4];
  const float* pnb  = (const float*)d_in[5];
  const float* alog = (const float*)d_in[6];
  const float* dbias= (const float*)d_in[7];
  const float* lgam = (const float*)d_in[8];

  char* ws = (char*)d_ws;
  size_t off = 0;
  auto alloc = [&](size_t bytes) -> void* {
    void* p = ws + off;
    off += (bytes + 255) & ~(size_t)255;
    return p;
  };
  float*          sc     = (float*)         alloc(1024);
  unsigned short* u16    = (unsigned short*)alloc((size_t)8192*1024*2);
  unsigned short* Wcat16 = (unsigned short*)alloc((size_t)4096*1024*2);
  unsigned short* Wout16 = (unsigned short*)alloc((size_t)1024*1024*2);
  unsigned short* P16    = (unsigned short*)alloc((size_t)8192*4096*2);
  unsigned short* yh16   = (unsigned short*)alloc((size_t)8192*1024*2);
  unsigned short* Hping  = (unsigned short*)alloc((size_t)2*1024*1024*2);
  unsigned short* Hpong  = (unsigned short*)alloc((size_t)2*1024*1024*2);
  float*          Asum   = (float*)alloc((size_t)B_*NCH*N_*4);
  float*          Ssum   = (float*)alloc((size_t)B_*NCH*N_*4);
  float*          Zent   = (float*)alloc((size_t)B_*NCH*N_*4);

  unsigned* barc = (unsigned*)(sc + 64);   // zeroed by k_convert_all
  unsigned* bart = (unsigned*)(sc + 80);

  k_convert_all<<<CONV_BLOCKS, 256, 0, stream>>>(u, Win, pnw, Wout, u16, Wcat16, Wout16, sc);

  // persistent spectral-norm chain (gram + SQN squarings + frob + final), one launch
  k_chain<<<512, 256, 0, stream>>>(Wcat16, Wout16, Hping, Hpong, sc, barc);

  // P = u @ [W_in; pn_w]^T  (bf16 out; sc[0] applied in tail)
  dim3 g1(4096/128, 8192/128);
  k_gemm<1><<<g1, 256, 0, stream>>>(u16, Wcat16, P16, 8192, 4096, 1024, sc, -1);

  // fused scan passes + output GEMM, one launch
  k_tail<<<512, 256, 0, stream>>>(P16, alog, dbias, pnb, lgam, sc, z0,
                                  Asum, Ssum, Zent, yh16, Wout16, (float*)d_out, bart);
}

// Round 6
// 325.962 us; speedup vs baseline: 3.7294x; 3.7294x over previous
//
#include <hip/hip_runtime.h>
#include <stdint.h>

#define B_ 4
#define T_ 2048
#define D_ 1024
#define N_ 1024
#define TC 32
#define NCH (T_/TC)
#define SQN 7   // squaring GEMMs after gram; +1 effective doubling via fused Frobenius

typedef __attribute__((ext_vector_type(4))) float f32x4;
typedef __attribute__((ext_vector_type(8))) short bf16x8;
typedef __attribute__((ext_vector_type(4))) unsigned short us4;

__device__ __forceinline__ unsigned short f2bf(float f){
  unsigned int u = __float_as_uint(f);
  return (unsigned short)((u + 0x7fffu + ((u >> 16) & 1u)) >> 16);
}
__device__ __forceinline__ float bf2f(unsigned short h){
  return __uint_as_float(((unsigned int)h) << 16);
}

// inverse spectral scale from trace chain (replaces k_final; ~30 VALU, run per block)
__device__ __forceinline__ float inv_scale(const float* __restrict__ sc, int z){
  float ll = 0.f, w = 1.f, t = 1.f;
  #pragma unroll
  for (int i = 0; i <= SQN; i++){
    t = sc[8 + 2*i + z];
    ll += w * __logf(t);
    w *= 0.5f;
  }
  float F = sc[8 + 2*(SQN+1) + z];
  ll += w * __logf(F / (t*t));
  float sig = fmaxf(__expf(0.5f * ll), 1e-5f);
  return 1.f / fmaxf(sig, 1.f);
}

// ---- fused fp32->bf16 conversion of all inputs + sc zero-init ----
#define U4    2097152   // 8192*1024/4
#define WIN4   262144   // 1024*1024/4
#define PNW4   786432   // 3072*1024/4
#define WOUT4  262144
#define CONV_BLOCKS ((U4 + WIN4 + PNW4 + WOUT4 + 255)/256)

__global__ void k_convert_all(const float* __restrict__ u, const float* __restrict__ Win,
                              const float* __restrict__ pnw, const float* __restrict__ Wout,
                              unsigned short* __restrict__ u16, unsigned short* __restrict__ Wcat16,
                              unsigned short* __restrict__ Wout16, float* __restrict__ sc){
  if (blockIdx.x == 0 && threadIdx.x < 64) sc[threadIdx.x] = 0.f;
  long i = (long)blockIdx.x * 256 + threadIdx.x;   // float4 index
  const float* src; unsigned short* dst; long o;
  if (i < U4)                      { src = u;    dst = u16;               o = i; }
  else if (i < U4+WIN4)            { src = Win;  dst = Wcat16;            o = i - U4; }
  else if (i < U4+WIN4+PNW4)       { src = pnw;  dst = Wcat16 + 1048576;  o = i - (U4+WIN4); }
  else if (i < U4+WIN4+PNW4+WOUT4) { src = Wout; dst = Wout16;            o = i - (U4+WIN4+PNW4); }
  else return;
  float4 v = ((const float4*)src)[o];
  us4 w;
  w.x = f2bf(v.x); w.y = f2bf(v.y); w.z = f2bf(v.z); w.w = f2bf(v.w);
  ((us4*)dst)[o] = w;
}

__device__ __forceinline__ void load_lds16(const unsigned short* g, unsigned short* l){
  __builtin_amdgcn_global_load_lds((const __attribute__((address_space(1))) void*)g,
                                   (__attribute__((address_space(3))) void*)l, 16, 0, 0);
}

// ==== triple-buffered GEMM: C[M,N] = (A[M,K=1024] @ B[N,K]^T) * scale ====
// BM=256, BN=128, BK=64, 8 waves (4Mx2N), 64x64 per wave.
// 3 LDS buffers (144KB): stage t+2 while computing t; ONE s_barrier per K-tile;
// counted vmcnt(6) -> prefetch loads span tiles, never drained in the main loop.
// Race-free: buf[(t+2)%3] was last read in tile t-1; every wave's reads of it
// completed before the barrier that ended tile t-1 (lgkmcnt(0) precedes MFMA).
template<int OUTBF16, int ZSC>
__global__ __launch_bounds__(512, 2) void k_big(
    const unsigned short* __restrict__ A,
    const unsigned short* __restrict__ Bmat,
    void* __restrict__ C0,
    int N, const float* __restrict__ sc)
{
  __shared__ alignas(16) unsigned short As3[3][256*64];
  __shared__ alignas(16) unsigned short Bs3[3][128*64];
  const int tid = threadIdx.x;
  const int wid = tid >> 6;
  const int lane = tid & 63;
  const int bn = blockIdx.x, bm = blockIdx.y;

  const int wr = wid >> 1;          // 0..3 : 64-row band
  const int wc = wid & 1;           // 0..1 : 64-col band
  const int frow = lane & 15;
  const int kgrp = lane >> 4;       // 0..3

  const float outscale = (ZSC >= 0) ? inv_scale(sc, ZSC) : 1.f;

  const unsigned short* Ab = A + (size_t)bm * 256 * 1024;
  const unsigned short* Bb = Bmat + (size_t)bn * 128 * 1024;

  // per-lane fragment byte offsets (t-invariant)
  int aoff[4][2], boff[4][2];
  #pragma unroll
  for (int m = 0; m < 4; m++){
    int r = wr*64 + m*16 + frow;
    #pragma unroll
    for (int ks = 0; ks < 2; ks++)
      aoff[m][ks] = r*128 + ((ks*64 + kgrp*16) ^ ((r & 7) << 4));
  }
  #pragma unroll
  for (int n = 0; n < 4; n++){
    int r = wc*64 + n*16 + frow;
    #pragma unroll
    for (int ks = 0; ks < 2; ks++)
      boff[n][ks] = r*128 + ((ks*64 + kgrp*16) ^ ((r & 7) << 4));
  }

  f32x4 acc[4][4] = {};

  auto stage = [&](int t){
    const int p = t % 3;
    #pragma unroll
    for (int l = 0; l < 4; l++){                 // A: 256x64 = 2048 granules
      int gi = l*512 + tid;
      int r = gi >> 3;
      int cb = (gi & 7) << 4;
      int colel = t*64 + (((cb ^ ((r & 7) << 4))) >> 1);
      load_lds16(Ab + (size_t)r*1024 + colel, &As3[p][gi*8]);
    }
    #pragma unroll
    for (int l = 0; l < 2; l++){                 // B: 128x64 = 1024 granules
      int gi = l*512 + tid;
      int r = gi >> 3;
      int cb = (gi & 7) << 4;
      int colel = t*64 + (((cb ^ ((r & 7) << 4))) >> 1);
      load_lds16(Bb + (size_t)r*1024 + colel, &Bs3[p][gi*8]);
    }
  };

  stage(0); stage(1);
  asm volatile("s_waitcnt vmcnt(6)" ::: "memory");   // tile 0 landed; tile 1 in flight
  __builtin_amdgcn_s_barrier();

  for (int t = 0; t < 16; ++t){
    if (t < 14) stage(t + 2);
    const int p = t % 3;
    const char* ab = (const char*)&As3[p][0];
    const char* bb = (const char*)&Bs3[p][0];
    bf16x8 af[4][2], bfv[4][2];
    #pragma unroll
    for (int m = 0; m < 4; m++)
      #pragma unroll
      for (int ks = 0; ks < 2; ks++)
        af[m][ks] = *(const bf16x8*)(ab + aoff[m][ks]);
    #pragma unroll
    for (int n = 0; n < 4; n++)
      #pragma unroll
      for (int ks = 0; ks < 2; ks++)
        bfv[n][ks] = *(const bf16x8*)(bb + boff[n][ks]);
    asm volatile("s_waitcnt lgkmcnt(0)" ::: "memory");
    __builtin_amdgcn_sched_barrier(0);
    __builtin_amdgcn_s_setprio(1);
    #pragma unroll
    for (int ks = 0; ks < 2; ks++)
      #pragma unroll
      for (int m = 0; m < 4; m++)
        #pragma unroll
        for (int n = 0; n < 4; n++)
          acc[m][n] = __builtin_amdgcn_mfma_f32_16x16x32_bf16(af[m][ks], bfv[n][ks], acc[m][n], 0, 0, 0);
    __builtin_amdgcn_s_setprio(0);
    __builtin_amdgcn_sched_barrier(0);
    if (t < 15){
      if (t < 14) asm volatile("s_waitcnt vmcnt(6)" ::: "memory");  // tile t+1 landed
      else        asm volatile("s_waitcnt vmcnt(0)" ::: "memory");  // last prefetch landed
      __builtin_amdgcn_s_barrier();
    }
  }

  const int row0 = bm*256 + wr*64;
  const int col0 = bn*128 + wc*64 + frow;
  char* C = (char*)C0;
  #pragma unroll
  for (int m = 0; m < 4; m++){
    #pragma unroll
    for (int n = 0; n < 4; n++){
      const int col = col0 + n*16;
      const int rb = row0 + m*16 + kgrp*4;
      #pragma unroll
      for (int j = 0; j < 4; j++){
        float v = acc[m][n][j] * outscale;
        if (OUTBF16) ((unsigned short*)C)[(size_t)(rb + j)*N + col] = f2bf(v);
        else         ((float*)C)[(size_t)(rb + j)*N + col] = v;
      }
    }
  }
}

// ---- squaring-chain GEMM: 64x64 tile, BK=128, double-buffered 2-phase prefetch ----
// step 0: C = A*A^T (gram). step>0: C = (A/t)^2. Trace -> sc[8+2*step+z].
// step==SQN also accumulates ||C||_F^2 -> sc[8+2*(SQN+1)+z] (free extra doubling).
__global__ __launch_bounds__(256) void k_sq(
    const unsigned short* __restrict__ A0, unsigned short* __restrict__ C0,
    const unsigned short* __restrict__ A1, unsigned short* __restrict__ C1,
    float* __restrict__ sc, int step)
{
  __shared__ alignas(16) unsigned short As0[64*128], Bs0[64*128];
  __shared__ alignas(16) unsigned short As1[64*128], Bs1[64*128];
  const int tid = threadIdx.x;
  const int wid = tid >> 6;
  const int lane = tid & 63;
  const int bn = blockIdx.x, bm = blockIdx.y, z = blockIdx.z;

  const unsigned short* A = z ? A1 : A0;
  unsigned short* C = z ? C1 : C0;
  float outscale = 1.f;
  if (step > 0){ float t = sc[8 + (step-1)*2 + z]; outscale = 1.f/(t*t); }

  const int wr = wid >> 1, wc = wid & 1;     // 32x32 quadrant per wave
  const int frow = lane & 15;
  const int kgrp = lane >> 4;

  const int srl = lane >> 4;
  const int sgr = lane & 15;
  const int swzr = wid*4 + srl;
  const int scol_e = ((sgr ^ swzr) << 3);

  const size_t Arow = (size_t)bm * 64;
  const size_t Brow = (size_t)bn * 64;

  f32x4 acc[2][2] = {};

  auto stage = [&](unsigned short* as, unsigned short* bs, int t){
    const int kt = t * 128;
    #pragma unroll
    for (int i = 0; i < 4; i++){
      int r = i*16 + wid*4 + srl;
      load_lds16(A + (Arow + r)*1024 + kt + scol_e, as + (i*16 + wid*4)*128);
      load_lds16(A + (Brow + r)*1024 + kt + scol_e, bs + (i*16 + wid*4)*128);
    }
  };

  auto compute = [&](const unsigned short* as, const unsigned short* bs){
    #pragma unroll
    for (int ks = 0; ks < 4; ks++){
      const int kb = ks*64 + kgrp*16;
      bf16x8 af[2], bfv[2];
      #pragma unroll
      for (int m = 0; m < 2; m++){
        int r = wr*32 + m*16 + frow;
        af[m] = *(const bf16x8*)((const char*)as + r*256 + (kb ^ (frow << 4)));
      }
      #pragma unroll
      for (int n2 = 0; n2 < 2; n2++){
        int r = wc*32 + n2*16 + frow;
        bfv[n2] = *(const bf16x8*)((const char*)bs + r*256 + (kb ^ (frow << 4)));
      }
      #pragma unroll
      for (int m = 0; m < 2; m++)
        #pragma unroll
        for (int n2 = 0; n2 < 2; n2++)
          acc[m][n2] = __builtin_amdgcn_mfma_f32_16x16x32_bf16(af[m], bfv[n2], acc[m][n2], 0, 0, 0);
    }
  };

  stage(As0, Bs0, 0);
  __syncthreads();
  for (int t2 = 0; t2 < 8; t2 += 2){
    if (t2 + 1 < 8) stage(As1, Bs1, t2 + 1);
    compute(As0, Bs0);
    __syncthreads();
    if (t2 + 2 < 8) stage(As0, Bs0, t2 + 2);
    compute(As1, Bs1);
    __syncthreads();
  }

  const int row0 = bm*64 + wr*32;
  const int col0 = bn*64 + wc*32 + frow;
  float fr = 0.f;
  #pragma unroll
  for (int m = 0; m < 2; m++){
    #pragma unroll
    for (int n2 = 0; n2 < 2; n2++){
      const int col = col0 + n2*16;
      const int rb = row0 + m*16 + kgrp*4;
      #pragma unroll
      for (int j = 0; j < 4; j++){
        float v = acc[m][n2][j] * outscale;
        C[(size_t)(rb + j)*1024 + col] = f2bf(v);
        fr += v*v;
      }
    }
  }
  if (bm == bn && wr == wc){
    int j = frow - kgrp*4;
    if (j >= 0 && j < 4){
      float d = (acc[0][0][j] + acc[1][1][j]) * outscale;
      atomicAdd(&sc[8 + step*2 + z], d);
    }
  }
  if (step == SQN){
    #pragma unroll
    for (int off = 32; off; off >>= 1) fr += __shfl_down(fr, off, 64);
    if (lane == 0) atomicAdd(&sc[8 + 2*(SQN+1) + z], fr);
  }
}

__device__ __forceinline__ float softplusf(float x){
  return (x > 0.f) ? (x + __logf(1.f + __expf(-x))) : __logf(1.f + __expf(x));
}
__device__ __forceinline__ float tanhfastf(float x){
  float e = __expf(2.f * x);
  return 1.f - 2.f/(e + 1.f);
}
__device__ __forceinline__ void abc_from(float pin, float draw, float braw, float craw,
    float alpha, float ginv, float& a_o, float& bu_o, float& c_o){
  float sp = softplusf(draw);
  float av = __expf(-sp * alpha);
  av = fminf(av, 1.f - 1e-4f);
  float bv = tanhfastf(braw);
  float cv = tanhfastf(craw);
  float p = av*av + cv*cv;
  float r = bv*bv;
  float q = av*bv;
  float pr = p - r;
  float disc = pr*pr + 4.f*q*q;
  float lam = 0.5f*(p + r + sqrtf(disc + 1e-12f));
  float sig = sqrtf(lam + 1e-12f);
  float inv = 1.f / fmaxf(sig, 1.f);
  a_o = av * inv;
  c_o = cv * inv;
  bu_o = (bv * inv) * (pin * ginv);
}

__global__ __launch_bounds__(256) void k_pass1(
    const unsigned short* __restrict__ P,
    const float* __restrict__ alog, const float* __restrict__ dbias,
    const float* __restrict__ pnb, const float* __restrict__ lgam,
    const float* __restrict__ sc,
    float* __restrict__ Asum, float* __restrict__ Ssum)
{
  const int tid = threadIdx.x;
  const int n0 = blockIdx.y*512 + tid*2;
  const int ch = blockIdx.x, b = blockIdx.z;
  const float ginv = __expf(lgam[0]) * inv_scale(sc, 0);
  float alpha[2], bd[2], bb[2], bc[2], A[2], S[2];
  #pragma unroll
  for (int j = 0; j < 2; j++){
    alpha[j] = softplusf(alog[n0+j]);
    bd[j] = dbias[n0+j] + pnb[n0+j];
    bb[j] = pnb[N_ + n0+j];
    bc[j] = pnb[2*N_ + n0+j];
    A[j] = 1.f; S[j] = 0.f;
  }
  const unsigned short* Pr = P + (size_t)(b*T_ + ch*TC) * (4*N_);
  #pragma unroll 4
  for (int i = 0; i < TC; i++){
    unsigned int vp = *(const unsigned int*)(Pr + n0);
    unsigned int vd = *(const unsigned int*)(Pr + N_ + n0);
    unsigned int vb = *(const unsigned int*)(Pr + 2*N_ + n0);
    unsigned int vc = *(const unsigned int*)(Pr + 3*N_ + n0);
    #pragma unroll
    for (int j = 0; j < 2; j++){
      float pin  = bf2f((unsigned short)(j ? (vp>>16) : (vp & 0xffffu)));
      float draw = bf2f((unsigned short)(j ? (vd>>16) : (vd & 0xffffu))) + bd[j];
      float braw = bf2f((unsigned short)(j ? (vb>>16) : (vb & 0xffffu))) + bb[j];
      float craw = bf2f((unsigned short)(j ? (vc>>16) : (vc & 0xffffu))) + bc[j];
      float a, bu, c;
      abc_from(pin, draw, braw, craw, alpha[j], ginv, a, bu, c);
      S[j] = fmaf(a, S[j], bu);
      A[j] *= a;
    }
    Pr += 4*N_;
  }
  const size_t idx = (size_t)(b*NCH + ch)*N_ + n0;
  Asum[idx] = A[0]; Asum[idx+1] = A[1];
  Ssum[idx] = S[0]; Ssum[idx+1] = S[1];
}

__global__ void k_pass2(const float* __restrict__ Asum, const float* __restrict__ Ssum,
                        const float* __restrict__ z0, float* __restrict__ Zent)
{
  const int n = blockIdx.x*256 + threadIdx.x;
  const int b = blockIdx.y;
  float z = z0[b*N_ + n];
  for (int ch = 0; ch < NCH; ch++){
    const size_t idx = (size_t)(b*NCH + ch)*N_ + n;
    Zent[idx] = z;
    z = fmaf(Asum[idx], z, Ssum[idx]);
  }
}

__global__ __launch_bounds__(256) void k_pass3(
    const unsigned short* __restrict__ P,
    const float* __restrict__ alog, const float* __restrict__ dbias,
    const float* __restrict__ pnb, const float* __restrict__ lgam,
    const float* __restrict__ sc, const float* __restrict__ Zent,
    unsigned short* __restrict__ yh)
{
  const int tid = threadIdx.x;
  const int n0 = blockIdx.y*512 + tid*2;
  const int ch = blockIdx.x, b = blockIdx.z;
  const float ginv = __expf(lgam[0]) * inv_scale(sc, 0);
  float alpha[2], bd[2], bb[2], bc[2], z[2];
  #pragma unroll
  for (int j = 0; j < 2; j++){
    alpha[j] = softplusf(alog[n0+j]);
    bd[j] = dbias[n0+j] + pnb[n0+j];
    bb[j] = pnb[N_ + n0+j];
    bc[j] = pnb[2*N_ + n0+j];
  }
  const size_t zidx = (size_t)(b*NCH + ch)*N_ + n0;
  z[0] = Zent[zidx]; z[1] = Zent[zidx+1];
  const unsigned short* Pr = P + (size_t)(b*T_ + ch*TC) * (4*N_);
  unsigned short* Y = yh + (size_t)(b*T_ + ch*TC)*N_ + n0;
  #pragma unroll 4
  for (int i = 0; i < TC; i++){
    unsigned int vp = *(const unsigned int*)(Pr + n0);
    unsigned int vd = *(const unsigned int*)(Pr + N_ + n0);
    unsigned int vb = *(const unsigned int*)(Pr + 2*N_ + n0);
    unsigned int vc = *(const unsigned int*)(Pr + 3*N_ + n0);
    unsigned int ow = 0;
    #pragma unroll
    for (int j = 0; j < 2; j++){
      float pin  = bf2f((unsigned short)(j ? (vp>>16) : (vp & 0xffffu)));
      float draw = bf2f((unsigned short)(j ? (vd>>16) : (vd & 0xffffu))) + bd[j];
      float braw = bf2f((unsigned short)(j ? (vb>>16) : (vb & 0xffffu))) + bb[j];
      float craw = bf2f((unsigned short)(j ? (vc>>16) : (vc & 0xffffu))) + bc[j];
      float a, bu, c;
      abc_from(pin, draw, braw, craw, alpha[j], ginv, a, bu, c);
      float yv = c * z[j];
      z[j] = fmaf(a, z[j], bu);
      ow |= ((unsigned int)f2bf(yv)) << (16*j);
    }
    *(unsigned int*)Y = ow;
    Y += N_;
    Pr += 4*N_;
  }
}

extern "C" void kernel_launch(void* const* d_in, const int* in_sizes, int n_in,
                              void* d_out, int out_size, void* d_ws, size_t ws_size,
                              hipStream_t stream)
{
  const float* u    = (const float*)d_in[0];
  const float* z0   = (const float*)d_in[1];
  const float* Win  = (const float*)d_in[2];
  const float* Wout = (const float*)d_in[3];
  const float* pnw  = (const float*)d_in[4];
  const float* pnb  = (const float*)d_in[5];
  const float* alog = (const float*)d_in[6];
  const float* dbias= (const float*)d_in[7];
  const float* lgam = (const float*)d_in[8];

  char* ws = (char*)d_ws;
  size_t off = 0;
  auto alloc = [&](size_t bytes) -> void* {
    void* p = ws + off;
    off += (bytes + 255) & ~(size_t)255;
    return p;
  };
  float*          sc     = (float*)         alloc(1024);
  unsigned short* u16    = (unsigned short*)alloc((size_t)8192*1024*2);
  unsigned short* Wcat16 = (unsigned short*)alloc((size_t)4096*1024*2);
  unsigned short* Wout16 = (unsigned short*)alloc((size_t)1024*1024*2);
  unsigned short* P16    = (unsigned short*)alloc((size_t)8192*4096*2);
  unsigned short* yh16   = (unsigned short*)alloc((size_t)8192*1024*2);
  unsigned short* Hping  = (unsigned short*)alloc((size_t)2*1024*1024*2);
  unsigned short* Hpong  = (unsigned short*)alloc((size_t)2*1024*1024*2);
  float*          Asum   = (float*)alloc((size_t)B_*NCH*N_*4);
  float*          Ssum   = (float*)alloc((size_t)B_*NCH*N_*4);
  float*          Zent   = (float*)alloc((size_t)B_*NCH*N_*4);

  k_convert_all<<<CONV_BLOCKS, 256, 0, stream>>>(u, Win, pnw, Wout, u16, Wcat16, Wout16, sc);

  // spectral-norm chains: gram (step 0) + SQN squarings; frob fused in last step
  dim3 gsq(16, 16, 2);
  k_sq<<<gsq, 256, 0, stream>>>(Wcat16, Hping, Wout16, Hping + (size_t)1024*1024, sc, 0);
  unsigned short* hin = Hping;
  unsigned short* hout = Hpong;
  for (int s = 1; s <= SQN; s++){
    k_sq<<<gsq, 256, 0, stream>>>(hin, hout, hin + (size_t)1024*1024, hout + (size_t)1024*1024, sc, s);
    unsigned short* t = hin; hin = hout; hout = t;
  }

  // P = u @ [W_in; pn_w]^T  (bf16 out; sc applied in pass1/pass3)
  dim3 g1(4096/128, 8192/256);
  k_big<1, -1><<<g1, 512, 0, stream>>>(u16, Wcat16, P16, 4096, sc);

  dim3 gp1(NCH, N_/512, B_);
  k_pass1<<<gp1, 256, 0, stream>>>(P16, alog, dbias, pnb, lgam, sc, Asum, Ssum);
  dim3 gp2(N_/256, B_);
  k_pass2<<<gp2, 256, 0, stream>>>(Asum, Ssum, z0, Zent);
  k_pass3<<<gp1, 256, 0, stream>>>(P16, alog, dbias, pnb, lgam, sc, Zent, yh16);

  // y = (y_hat @ W_out^T) * inv_scale(sc,1)  (fp32 out)
  dim3 g2(1024/128, 8192/256);
  k_big<0, 1><<<g2, 512, 0, stream>>>(yh16, Wout16, d_out, 1024, sc);
}

// Round 7
// 314.292 us; speedup vs baseline: 3.8679x; 1.0371x over previous
//
#include <hip/hip_runtime.h>
#include <stdint.h>

#define B_ 4
#define T_ 2048
#define D_ 1024
#define N_ 1024
#define TC 16
#define NCH (T_/TC)
#define SQN 7   // squaring GEMMs after gram; +1 effective doubling via fused Frobenius

typedef __attribute__((ext_vector_type(4))) float f32x4;
typedef __attribute__((ext_vector_type(8))) short bf16x8;
typedef __attribute__((ext_vector_type(4))) unsigned short us4;

__device__ __forceinline__ unsigned short f2bf(float f){
  unsigned int u = __float_as_uint(f);
  return (unsigned short)((u + 0x7fffu + ((u >> 16) & 1u)) >> 16);
}
__device__ __forceinline__ float bf2f(unsigned short h){
  return __uint_as_float(((unsigned int)h) << 16);
}

// inverse spectral scale from trace chain (z=0: W_in, z=1: W_out)
__device__ __forceinline__ float inv_scale(const float* __restrict__ sc, int z){
  float ll = 0.f, w = 1.f, t = 1.f;
  #pragma unroll
  for (int i = 0; i <= SQN; i++){
    t = sc[8 + 2*i + z];
    ll += w * __logf(t);
    w *= 0.5f;
  }
  float F = sc[8 + 2*(SQN+1) + z];
  ll += w * __logf(F / (t*t));
  float sig = fmaxf(__expf(0.5f * ll), 1e-5f);
  return 1.f / fmaxf(sig, 1.f);
}

// ---- fused fp32->bf16 conversion of all inputs + sc zero-init ----
#define U4    2097152   // 8192*1024/4
#define WIN4   262144   // 1024*1024/4
#define PNW4   786432   // 3072*1024/4
#define WOUT4  262144
#define CONV_BLOCKS ((U4 + WIN4 + PNW4 + WOUT4 + 255)/256)

__global__ void k_convert_all(const float* __restrict__ u, const float* __restrict__ Win,
                              const float* __restrict__ pnw, const float* __restrict__ Wout,
                              unsigned short* __restrict__ u16, unsigned short* __restrict__ Wcat16,
                              unsigned short* __restrict__ Wout16, float* __restrict__ sc){
  if (blockIdx.x == 0 && threadIdx.x < 64) sc[threadIdx.x] = 0.f;
  long i = (long)blockIdx.x * 256 + threadIdx.x;   // float4 index
  const float* src; unsigned short* dst; long o;
  if (i < U4)                      { src = u;    dst = u16;               o = i; }
  else if (i < U4+WIN4)            { src = Win;  dst = Wcat16;            o = i - U4; }
  else if (i < U4+WIN4+PNW4)       { src = pnw;  dst = Wcat16 + 1048576;  o = i - (U4+WIN4); }
  else if (i < U4+WIN4+PNW4+WOUT4) { src = Wout; dst = Wout16;            o = i - (U4+WIN4+PNW4); }
  else return;
  float4 v = ((const float4*)src)[o];
  us4 w;
  w.x = f2bf(v.x); w.y = f2bf(v.y); w.z = f2bf(v.z); w.w = f2bf(v.w);
  ((us4*)dst)[o] = w;
}

__device__ __forceinline__ void load_lds16(const unsigned short* g, unsigned short* l){
  __builtin_amdgcn_global_load_lds((const __attribute__((address_space(1))) void*)g,
                                   (__attribute__((address_space(3))) void*)l, 16, 0, 0);
}

// ---- big GEMM: C[M,N] = (A[M,K] * B[N,K]^T) * (step>=0 ? inv_scale(step) : 1) ----
// 128x128 tile, proven m97-structure (R1/R3 verified at ~89.5us for the P-GEMM).
template<int OUTBF16>
__global__ __launch_bounds__(256) void k_gemm(
    const unsigned short* __restrict__ A,
    const unsigned short* __restrict__ Bmat,
    void* __restrict__ C0,
    int M, int N, int K,
    const float* __restrict__ sc, int step)
{
  __shared__ alignas(16) unsigned short As[128*64];
  __shared__ alignas(16) unsigned short Bs[128*64];
  const int tid = threadIdx.x;
  const int wid = tid >> 6;
  const int lane = tid & 63;
  const int bn = blockIdx.x, bm = blockIdx.y;

  char* C = (char*)C0;
  float outscale = (step >= 0) ? inv_scale(sc, step) : 1.f;

  const int wr = wid >> 1, wc = wid & 1;
  const int rg = lane >> 3;
  const int cby = (lane & 7) << 4;
  const int srow0 = wid * 32;
  const int frow = lane & 15;
  const int kgrp = lane >> 4;

  const size_t Abase = (size_t)bm * 128 * K;
  const size_t Bbase = (size_t)bn * 128 * K;

  f32x4 acc[4][4] = {};

  for (int kt = 0; kt < K; kt += 64){
    #pragma unroll
    for (int i = 0; i < 4; i++){
      int r = srow0 + i*8 + rg;
      int cb = cby ^ ((r & 7) << 4);
      load_lds16(A    + Abase + (size_t)r*K + kt + (cb >> 1), As + (srow0 + i*8)*64);
      load_lds16(Bmat + Bbase + (size_t)r*K + kt + (cb >> 1), Bs + (srow0 + i*8)*64);
    }
    __syncthreads();
    #pragma unroll
    for (int kk = 0; kk < 2; kk++){
      const int kbyte = kk*64 + kgrp*16;
      bf16x8 af[4], bfv[4];
      #pragma unroll
      for (int m = 0; m < 4; m++){
        int r = wr*64 + m*16 + frow;
        af[m] = *(const bf16x8*)((const char*)As + r*128 + (kbyte ^ ((r & 7) << 4)));
      }
      #pragma unroll
      for (int n2 = 0; n2 < 4; n2++){
        int r = wc*64 + n2*16 + frow;
        bfv[n2] = *(const bf16x8*)((const char*)Bs + r*128 + (kbyte ^ ((r & 7) << 4)));
      }
      #pragma unroll
      for (int m = 0; m < 4; m++)
        #pragma unroll
        for (int n2 = 0; n2 < 4; n2++)
          acc[m][n2] = __builtin_amdgcn_mfma_f32_16x16x32_bf16(af[m], bfv[n2], acc[m][n2], 0, 0, 0);
    }
    __syncthreads();
  }

  const int row0 = bm*128 + wr*64;
  const int col0 = bn*128 + wc*64 + frow;
  #pragma unroll
  for (int m = 0; m < 4; m++){
    #pragma unroll
    for (int n2 = 0; n2 < 4; n2++){
      const int col = col0 + n2*16;
      const int rb = row0 + m*16 + kgrp*4;
      #pragma unroll
      for (int j = 0; j < 4; j++){
        float v = acc[m][n2][j] * outscale;
        if (OUTBF16) ((unsigned short*)C)[(size_t)(rb + j)*N + col] = f2bf(v);
        else         ((float*)C)[(size_t)(rb + j)*N + col] = v;
      }
    }
  }
}

// ---- squaring-chain GEMM: 64x64 tile, BK=128, double-buffered 2-phase prefetch ----
// step 0: C = A*A^T (gram). step>0: C = (A/t)^2. Trace -> sc[8+2*step+z].
// step==SQN also accumulates ||C||_F^2 -> sc[8+2*(SQN+1)+z] (free extra doubling).
__global__ __launch_bounds__(256) void k_sq(
    const unsigned short* __restrict__ A0, unsigned short* __restrict__ C0,
    const unsigned short* __restrict__ A1, unsigned short* __restrict__ C1,
    float* __restrict__ sc, int step)
{
  __shared__ alignas(16) unsigned short As0[64*128], Bs0[64*128];
  __shared__ alignas(16) unsigned short As1[64*128], Bs1[64*128];
  const int tid = threadIdx.x;
  const int wid = tid >> 6;
  const int lane = tid & 63;
  const int bn = blockIdx.x, bm = blockIdx.y, z = blockIdx.z;

  const unsigned short* A = z ? A1 : A0;
  unsigned short* C = z ? C1 : C0;
  float outscale = 1.f;
  if (step > 0){ float t = sc[8 + (step-1)*2 + z]; outscale = 1.f/(t*t); }

  const int wr = wid >> 1, wc = wid & 1;     // 32x32 quadrant per wave
  const int frow = lane & 15;
  const int kgrp = lane >> 4;

  const int srl = lane >> 4;
  const int sgr = lane & 15;
  const int swzr = wid*4 + srl;
  const int scol_e = ((sgr ^ swzr) << 3);

  const size_t Arow = (size_t)bm * 64;
  const size_t Brow = (size_t)bn * 64;

  f32x4 acc[2][2] = {};

  auto stage = [&](unsigned short* as, unsigned short* bs, int t){
    const int kt = t * 128;
    #pragma unroll
    for (int i = 0; i < 4; i++){
      int r = i*16 + wid*4 + srl;
      load_lds16(A + (Arow + r)*1024 + kt + scol_e, as + (i*16 + wid*4)*128);
      load_lds16(A + (Brow + r)*1024 + kt + scol_e, bs + (i*16 + wid*4)*128);
    }
  };

  auto compute = [&](const unsigned short* as, const unsigned short* bs){
    #pragma unroll
    for (int ks = 0; ks < 4; ks++){
      const int kb = ks*64 + kgrp*16;
      bf16x8 af[2], bfv[2];
      #pragma unroll
      for (int m = 0; m < 2; m++){
        int r = wr*32 + m*16 + frow;
        af[m] = *(const bf16x8*)((const char*)as + r*256 + (kb ^ (frow << 4)));
      }
      #pragma unroll
      for (int n2 = 0; n2 < 2; n2++){
        int r = wc*32 + n2*16 + frow;
        bfv[n2] = *(const bf16x8*)((const char*)bs + r*256 + (kb ^ (frow << 4)));
      }
      #pragma unroll
      for (int m = 0; m < 2; m++)
        #pragma unroll
        for (int n2 = 0; n2 < 2; n2++)
          acc[m][n2] = __builtin_amdgcn_mfma_f32_16x16x32_bf16(af[m], bfv[n2], acc[m][n2], 0, 0, 0);
    }
  };

  stage(As0, Bs0, 0);
  __syncthreads();
  for (int t2 = 0; t2 < 8; t2 += 2){
    if (t2 + 1 < 8) stage(As1, Bs1, t2 + 1);
    compute(As0, Bs0);
    __syncthreads();
    if (t2 + 2 < 8) stage(As0, Bs0, t2 + 2);
    compute(As1, Bs1);
    __syncthreads();
  }

  const int row0 = bm*64 + wr*32;
  const int col0 = bn*64 + wc*32 + frow;
  float fr = 0.f;
  #pragma unroll
  for (int m = 0; m < 2; m++){
    #pragma unroll
    for (int n2 = 0; n2 < 2; n2++){
      const int col = col0 + n2*16;
      const int rb = row0 + m*16 + kgrp*4;
      #pragma unroll
      for (int j = 0; j < 4; j++){
        float v = acc[m][n2][j] * outscale;
        C[(size_t)(rb + j)*1024 + col] = f2bf(v);
        fr += v*v;
      }
    }
  }
  if (bm == bn && wr == wc){
    int j = frow - kgrp*4;
    if (j >= 0 && j < 4){
      float d = (acc[0][0][j] + acc[1][1][j]) * outscale;
      atomicAdd(&sc[8 + step*2 + z], d);
    }
  }
  if (step == SQN){
    #pragma unroll
    for (int off = 32; off; off >>= 1) fr += __shfl_down(fr, off, 64);
    if (lane == 0) atomicAdd(&sc[8 + 2*(SQN+1) + z], fr);
  }
}

__device__ __forceinline__ float softplusf(float x){
  return (x > 0.f) ? (x + __logf(1.f + __expf(-x))) : __logf(1.f + __expf(x));
}
__device__ __forceinline__ float tanhfastf(float x){
  float e = __expf(2.f * x);
  return 1.f - 2.f/(e + 1.f);
}
__device__ __forceinline__ void abc_from(float pin, float draw, float braw, float craw,
    float alpha, float ginv, float& a_o, float& bu_o, float& c_o){
  float sp = softplusf(draw);
  float av = __expf(-sp * alpha);
  av = fminf(av, 1.f - 1e-4f);
  float bv = tanhfastf(braw);
  float cv = tanhfastf(craw);
  float p = av*av + cv*cv;
  float r = bv*bv;
  float q = av*bv;
  float pr = p - r;
  float disc = pr*pr + 4.f*q*q;
  float lam = 0.5f*(p + r + sqrtf(disc + 1e-12f));
  float sig = sqrtf(lam + 1e-12f);
  float inv = 1.f / fmaxf(sig, 1.f);
  a_o = av * inv;
  c_o = cv * inv;
  bu_o = (bv * inv) * (pin * ginv);
}

// ---- pass1: per-chunk (A,S), 8B/lane loads (G13), 4 n's per thread ----
// grid (NCH=128, B_), 256 thr; each block covers all 1024 n of one (b, chunk).
__global__ __launch_bounds__(256) void k_pass1(
    const unsigned short* __restrict__ P,
    const float* __restrict__ alog, const float* __restrict__ dbias,
    const float* __restrict__ pnb, const float* __restrict__ lgam,
    const float* __restrict__ sc,
    float* __restrict__ Asum, float* __restrict__ Ssum)
{
  const int tid = threadIdx.x;
  const int n0 = tid*4;
  const int ch = blockIdx.x, b = blockIdx.y;
  const float ginv = __expf(lgam[0]) * inv_scale(sc, 0);
  float alpha[4], bd[4], bb[4], bc[4], A[4], S[4];
  #pragma unroll
  for (int j = 0; j < 4; j++){
    alpha[j] = softplusf(alog[n0+j]);
    bd[j] = dbias[n0+j] + pnb[n0+j];
    bb[j] = pnb[N_ + n0+j];
    bc[j] = pnb[2*N_ + n0+j];
    A[j] = 1.f; S[j] = 0.f;
  }
  const unsigned short* Pr = P + (size_t)(b*T_ + ch*TC) * (4*N_);
  #pragma unroll 2
  for (int i = 0; i < TC; i++){
    us4 vp = *(const us4*)(Pr + n0);
    us4 vd = *(const us4*)(Pr + N_ + n0);
    us4 vb = *(const us4*)(Pr + 2*N_ + n0);
    us4 vc = *(const us4*)(Pr + 3*N_ + n0);
    #pragma unroll
    for (int j = 0; j < 4; j++){
      float a, bu, c;
      abc_from(bf2f(vp[j]), bf2f(vd[j]) + bd[j], bf2f(vb[j]) + bb[j], bf2f(vc[j]) + bc[j],
               alpha[j], ginv, a, bu, c);
      S[j] = fmaf(a, S[j], bu);
      A[j] *= a;
    }
    Pr += 4*N_;
  }
  const size_t idx = (size_t)(b*NCH + ch)*N_ + n0;
  #pragma unroll
  for (int j = 0; j < 4; j++){ Asum[idx+j] = A[j]; Ssum[idx+j] = S[j]; }
}

__global__ void k_pass2(const float* __restrict__ Asum, const float* __restrict__ Ssum,
                        const float* __restrict__ z0, float* __restrict__ Zent)
{
  const int n = blockIdx.x*256 + threadIdx.x;
  const int b = blockIdx.y;
  float z = z0[b*N_ + n];
  for (int ch = 0; ch < NCH; ch++){
    const size_t idx = (size_t)(b*NCH + ch)*N_ + n;
    Zent[idx] = z;
    z = fmaf(Asum[idx], z, Ssum[idx]);
  }
}

// ---- pass3: recompute gates, emit y_hat = c * z(before); 8B/lane ----
__global__ __launch_bounds__(256) void k_pass3(
    const unsigned short* __restrict__ P,
    const float* __restrict__ alog, const float* __restrict__ dbias,
    const float* __restrict__ pnb, const float* __restrict__ lgam,
    const float* __restrict__ sc, const float* __restrict__ Zent,
    unsigned short* __restrict__ yh)
{
  const int tid = threadIdx.x;
  const int n0 = tid*4;
  const int ch = blockIdx.x, b = blockIdx.y;
  const float ginv = __expf(lgam[0]) * inv_scale(sc, 0);
  float alpha[4], bd[4], bb[4], bc[4], z[4];
  #pragma unroll
  for (int j = 0; j < 4; j++){
    alpha[j] = softplusf(alog[n0+j]);
    bd[j] = dbias[n0+j] + pnb[n0+j];
    bb[j] = pnb[N_ + n0+j];
    bc[j] = pnb[2*N_ + n0+j];
  }
  const size_t zidx = (size_t)(b*NCH + ch)*N_ + n0;
  #pragma unroll
  for (int j = 0; j < 4; j++) z[j] = Zent[zidx+j];
  const unsigned short* Pr = P + (size_t)(b*T_ + ch*TC) * (4*N_);
  unsigned short* Y = yh + (size_t)(b*T_ + ch*TC)*N_ + n0;
  #pragma unroll 2
  for (int i = 0; i < TC; i++){
    us4 vp = *(const us4*)(Pr + n0);
    us4 vd = *(const us4*)(Pr + N_ + n0);
    us4 vb = *(const us4*)(Pr + 2*N_ + n0);
    us4 vc = *(const us4*)(Pr + 3*N_ + n0);
    us4 ow;
    #pragma unroll
    for (int j = 0; j < 4; j++){
      float a, bu, c;
      abc_from(bf2f(vp[j]), bf2f(vd[j]) + bd[j], bf2f(vb[j]) + bb[j], bf2f(vc[j]) + bc[j],
               alpha[j], ginv, a, bu, c);
      float yv = c * z[j];
      z[j] = fmaf(a, z[j], bu);
      ow[j] = f2bf(yv);
    }
    *(us4*)Y = ow;
    Y += N_;
    Pr += 4*N_;
  }
}

extern "C" void kernel_launch(void* const* d_in, const int* in_sizes, int n_in,
                              void* d_out, int out_size, void* d_ws, size_t ws_size,
                              hipStream_t stream)
{
  const float* u    = (const float*)d_in[0];
  const float* z0   = (const float*)d_in[1];
  const float* Win  = (const float*)d_in[2];
  const float* Wout = (const float*)d_in[3];
  const float* pnw  = (const float*)d_in[4];
  const float* pnb  = (const float*)d_in[5];
  const float* alog = (const float*)d_in[6];
  const float* dbias= (const float*)d_in[7];
  const float* lgam = (const float*)d_in[8];

  char* ws = (char*)d_ws;
  size_t off = 0;
  auto alloc = [&](size_t bytes) -> void* {
    void* p = ws + off;
    off += (bytes + 255) & ~(size_t)255;
    return p;
  };
  float*          sc     = (float*)         alloc(1024);
  unsigned short* u16    = (unsigned short*)alloc((size_t)8192*1024*2);
  unsigned short* Wcat16 = (unsigned short*)alloc((size_t)4096*1024*2);
  unsigned short* Wout16 = (unsigned short*)alloc((size_t)1024*1024*2);
  unsigned short* P16    = (unsigned short*)alloc((size_t)8192*4096*2);
  unsigned short* yh16   = (unsigned short*)alloc((size_t)8192*1024*2);
  unsigned short* Hping  = (unsigned short*)alloc((size_t)2*1024*1024*2);
  unsigned short* Hpong  = (unsigned short*)alloc((size_t)2*1024*1024*2);
  float*          Asum   = (float*)alloc((size_t)B_*NCH*N_*4);
  float*          Ssum   = (float*)alloc((size_t)B_*NCH*N_*4);
  float*          Zent   = (float*)alloc((size_t)B_*NCH*N_*4);

  k_convert_all<<<CONV_BLOCKS, 256, 0, stream>>>(u, Win, pnw, Wout, u16, Wcat16, Wout16, sc);

  // spectral-norm chains: gram (step 0) + SQN squarings; frob fused in last step
  dim3 gsq(16, 16, 2);
  k_sq<<<gsq, 256, 0, stream>>>(Wcat16, Hping, Wout16, Hping + (size_t)1024*1024, sc, 0);
  unsigned short* hin = Hping;
  unsigned short* hout = Hpong;
  for (int s = 1; s <= SQN; s++){
    k_sq<<<gsq, 256, 0, stream>>>(hin, hout, hin + (size_t)1024*1024, hout + (size_t)1024*1024, sc, s);
    unsigned short* t = hin; hin = hout; hout = t;
  }

  // P = u @ [W_in; pn_w]^T  (bf16 out; inv_scale applied in pass1/pass3)
  dim3 g1(4096/128, 8192/128);
  k_gemm<1><<<g1, 256, 0, stream>>>(u16, Wcat16, P16, 8192, 4096, 1024, sc, -1);

  dim3 gp1(NCH, B_);
  k_pass1<<<gp1, 256, 0, stream>>>(P16, alog, dbias, pnb, lgam, sc, Asum, Ssum);
  dim3 gp2(N_/256, B_);
  k_pass2<<<gp2, 256, 0, stream>>>(Asum, Ssum, z0, Zent);
  k_pass3<<<gp1, 256, 0, stream>>>(P16, alog, dbias, pnb, lgam, sc, Zent, yh16);

  // y = (y_hat @ W_out^T) * inv_scale(sc,1)  (fp32 out)
  dim3 g2(1024/128, 8192/128);
  k_gemm<0><<<g2, 256, 0, stream>>>(yh16, Wout16, d_out, 8192, 1024, 1024, sc, 1);
}

// Round 8
// 300.233 us; speedup vs baseline: 4.0490x; 1.0468x over previous
//
#include <hip/hip_runtime.h>
#include <stdint.h>

#define B_ 4
#define T_ 2048
#define D_ 1024
#define N_ 1024
#define TC 16
#define NCH (T_/TC)
#define SQN 6   // squaring GEMMs after gram; +1 effective doubling via fused Frobenius

typedef __attribute__((ext_vector_type(4))) float f32x4;
typedef __attribute__((ext_vector_type(8))) short bf16x8;
typedef __attribute__((ext_vector_type(4))) unsigned short us4;

__device__ __forceinline__ unsigned short f2bf(float f){
  unsigned int u = __float_as_uint(f);
  return (unsigned short)((u + 0x7fffu + ((u >> 16) & 1u)) >> 16);
}
__device__ __forceinline__ float bf2f(unsigned short h){
  return __uint_as_float(((unsigned int)h) << 16);
}

// inverse spectral scale from trace chain (z=0: W_in, z=1: W_out)
__device__ __forceinline__ float inv_scale(const float* __restrict__ sc, int z){
  float ll = 0.f, w = 1.f, t = 1.f;
  #pragma unroll
  for (int i = 0; i <= SQN; i++){
    t = sc[8 + 2*i + z];
    ll += w * __logf(t);
    w *= 0.5f;
  }
  float F = sc[8 + 2*(SQN+1) + z];
  ll += w * __logf(F / (t*t));
  float sig = fmaxf(__expf(0.5f * ll), 1e-5f);
  return 1.f / fmaxf(sig, 1.f);
}

// ---- fused fp32->bf16 conversion of all inputs + sc zero-init ----
#define U4    2097152   // 8192*1024/4
#define WIN4   262144   // 1024*1024/4
#define PNW4   786432   // 3072*1024/4
#define WOUT4  262144
#define CONV_BLOCKS ((U4 + WIN4 + PNW4 + WOUT4 + 255)/256)

__global__ void k_convert_all(const float* __restrict__ u, const float* __restrict__ Win,
                              const float* __restrict__ pnw, const float* __restrict__ Wout,
                              unsigned short* __restrict__ u16, unsigned short* __restrict__ Wcat16,
                              unsigned short* __restrict__ Wout16, float* __restrict__ sc){
  if (blockIdx.x == 0 && threadIdx.x < 64) sc[threadIdx.x] = 0.f;
  long i = (long)blockIdx.x * 256 + threadIdx.x;   // float4 index
  const float* src; unsigned short* dst; long o;
  if (i < U4)                      { src = u;    dst = u16;               o = i; }
  else if (i < U4+WIN4)            { src = Win;  dst = Wcat16;            o = i - U4; }
  else if (i < U4+WIN4+PNW4)       { src = pnw;  dst = Wcat16 + 1048576;  o = i - (U4+WIN4); }
  else if (i < U4+WIN4+PNW4+WOUT4) { src = Wout; dst = Wout16;            o = i - (U4+WIN4+PNW4); }
  else return;
  float4 v = ((const float4*)src)[o];
  us4 w;
  w.x = f2bf(v.x); w.y = f2bf(v.y); w.z = f2bf(v.z); w.w = f2bf(v.w);
  ((us4*)dst)[o] = w;
}

__device__ __forceinline__ void load_lds16(const unsigned short* g, unsigned short* l){
  __builtin_amdgcn_global_load_lds((const __attribute__((address_space(1))) void*)g,
                                   (__attribute__((address_space(3))) void*)l, 16, 0, 0);
}

// ---- big GEMM: C[M,N] = (A[M,K] * B[N,K]^T) * (step>=0 ? inv_scale(step) : 1) ----
// 128x128 tile, proven m97-structure (~89.5us for the P-GEMM).
template<int OUTBF16>
__global__ __launch_bounds__(256) void k_gemm(
    const unsigned short* __restrict__ A,
    const unsigned short* __restrict__ Bmat,
    void* __restrict__ C0,
    int M, int N, int K,
    const float* __restrict__ sc, int step)
{
  __shared__ alignas(16) unsigned short As[128*64];
  __shared__ alignas(16) unsigned short Bs[128*64];
  const int tid = threadIdx.x;
  const int wid = tid >> 6;
  const int lane = tid & 63;
  const int bn = blockIdx.x, bm = blockIdx.y;

  char* C = (char*)C0;
  float outscale = (step >= 0) ? inv_scale(sc, step) : 1.f;

  const int wr = wid >> 1, wc = wid & 1;
  const int rg = lane >> 3;
  const int cby = (lane & 7) << 4;
  const int srow0 = wid * 32;
  const int frow = lane & 15;
  const int kgrp = lane >> 4;

  const size_t Abase = (size_t)bm * 128 * K;
  const size_t Bbase = (size_t)bn * 128 * K;

  f32x4 acc[4][4] = {};

  for (int kt = 0; kt < K; kt += 64){
    #pragma unroll
    for (int i = 0; i < 4; i++){
      int r = srow0 + i*8 + rg;
      int cb = cby ^ ((r & 7) << 4);
      load_lds16(A    + Abase + (size_t)r*K + kt + (cb >> 1), As + (srow0 + i*8)*64);
      load_lds16(Bmat + Bbase + (size_t)r*K + kt + (cb >> 1), Bs + (srow0 + i*8)*64);
    }
    __syncthreads();
    #pragma unroll
    for (int kk = 0; kk < 2; kk++){
      const int kbyte = kk*64 + kgrp*16;
      bf16x8 af[4], bfv[4];
      #pragma unroll
      for (int m = 0; m < 4; m++){
        int r = wr*64 + m*16 + frow;
        af[m] = *(const bf16x8*)((const char*)As + r*128 + (kbyte ^ ((r & 7) << 4)));
      }
      #pragma unroll
      for (int n2 = 0; n2 < 4; n2++){
        int r = wc*64 + n2*16 + frow;
        bfv[n2] = *(const bf16x8*)((const char*)Bs + r*128 + (kbyte ^ ((r & 7) << 4)));
      }
      #pragma unroll
      for (int m = 0; m < 4; m++)
        #pragma unroll
        for (int n2 = 0; n2 < 4; n2++)
          acc[m][n2] = __builtin_amdgcn_mfma_f32_16x16x32_bf16(af[m], bfv[n2], acc[m][n2], 0, 0, 0);
    }
    __syncthreads();
  }

  const int row0 = bm*128 + wr*64;
  const int col0 = bn*128 + wc*64 + frow;
  #pragma unroll
  for (int m = 0; m < 4; m++){
    #pragma unroll
    for (int n2 = 0; n2 < 4; n2++){
      const int col = col0 + n2*16;
      const int rb = row0 + m*16 + kgrp*4;
      #pragma unroll
      for (int j = 0; j < 4; j++){
        float v = acc[m][n2][j] * outscale;
        if (OUTBF16) ((unsigned short*)C)[(size_t)(rb + j)*N + col] = f2bf(v);
        else         ((float*)C)[(size_t)(rb + j)*N + col] = v;
      }
    }
  }
}

// ---- triangular squaring-chain GEMM: C = X*X^T is SYMMETRIC -> compute upper
// triangle only (136 of 256 tiles/z), mirror-write transposed tile for bm!=bn.
// 64x64 tile, BK=128, double-buffered. Trace -> sc[8+2*step+z]; step==SQN also
// accumulates ||C||_F^2 -> sc[8+2*(SQN+1)+z] (off-diag tiles count twice).
__global__ __launch_bounds__(256) void k_sq(
    const unsigned short* __restrict__ A0, unsigned short* __restrict__ C0,
    const unsigned short* __restrict__ A1, unsigned short* __restrict__ C1,
    float* __restrict__ sc, int step)
{
  __shared__ alignas(16) unsigned short As0[64*128], Bs0[64*128];
  __shared__ alignas(16) unsigned short As1[64*128], Bs1[64*128];
  const int tid = threadIdx.x;
  const int wid = tid >> 6;
  const int lane = tid & 63;
  const int z = blockIdx.z;

  // triangular decode: blockIdx.x in [0,136) -> (bm<=bn)
  int x = blockIdx.x, bm = 0;
  while (x >= 16 - bm){ x -= 16 - bm; bm++; }
  const int bn = bm + x;

  const unsigned short* A = z ? A1 : A0;
  unsigned short* C = z ? C1 : C0;
  float outscale = 1.f;
  if (step > 0){ float t = sc[8 + (step-1)*2 + z]; outscale = 1.f/(t*t); }

  const int wr = wid >> 1, wc = wid & 1;     // 32x32 quadrant per wave
  const int frow = lane & 15;
  const int kgrp = lane >> 4;

  const int srl = lane >> 4;
  const int sgr = lane & 15;
  const int swzr = wid*4 + srl;
  const int scol_e = ((sgr ^ swzr) << 3);

  const size_t Arow = (size_t)bm * 64;
  const size_t Brow = (size_t)bn * 64;

  f32x4 acc[2][2] = {};

  auto stage = [&](unsigned short* as, unsigned short* bs, int t){
    const int kt = t * 128;
    #pragma unroll
    for (int i = 0; i < 4; i++){
      int r = i*16 + wid*4 + srl;
      load_lds16(A + (Arow + r)*1024 + kt + scol_e, as + (i*16 + wid*4)*128);
      load_lds16(A + (Brow + r)*1024 + kt + scol_e, bs + (i*16 + wid*4)*128);
    }
  };

  auto compute = [&](const unsigned short* as, const unsigned short* bs){
    #pragma unroll
    for (int ks = 0; ks < 4; ks++){
      const int kb = ks*64 + kgrp*16;
      bf16x8 af[2], bfv[2];
      #pragma unroll
      for (int m = 0; m < 2; m++){
        int r = wr*32 + m*16 + frow;
        af[m] = *(const bf16x8*)((const char*)as + r*256 + (kb ^ (frow << 4)));
      }
      #pragma unroll
      for (int n2 = 0; n2 < 2; n2++){
        int r = wc*32 + n2*16 + frow;
        bfv[n2] = *(const bf16x8*)((const char*)bs + r*256 + (kb ^ (frow << 4)));
      }
      #pragma unroll
      for (int m = 0; m < 2; m++)
        #pragma unroll
        for (int n2 = 0; n2 < 2; n2++)
          acc[m][n2] = __builtin_amdgcn_mfma_f32_16x16x32_bf16(af[m], bfv[n2], acc[m][n2], 0, 0, 0);
    }
  };

  stage(As0, Bs0, 0);
  __syncthreads();
  for (int t2 = 0; t2 < 8; t2 += 2){
    if (t2 + 1 < 8) stage(As1, Bs1, t2 + 1);
    compute(As0, Bs0);
    __syncthreads();
    if (t2 + 2 < 8) stage(As0, Bs0, t2 + 2);
    compute(As1, Bs1);
    __syncthreads();
  }

  const int row0 = bm*64 + wr*32;
  const int col0 = bn*64 + wc*32 + frow;
  float fr = 0.f;
  #pragma unroll
  for (int m = 0; m < 2; m++){
    #pragma unroll
    for (int n2 = 0; n2 < 2; n2++){
      const int col = col0 + n2*16;
      const int rb = row0 + m*16 + kgrp*4;
      us4 tw;
      #pragma unroll
      for (int j = 0; j < 4; j++){
        float v = acc[m][n2][j] * outscale;
        unsigned short h = f2bf(v);
        C[(size_t)(rb + j)*1024 + col] = h;   // normal (upper-tri) element
        tw[j] = h;
        fr += v*v;
      }
      if (bm != bn)                            // mirror: C[col][rb..rb+3]
        *(us4*)(C + (size_t)col*1024 + rb) = tw;
    }
  }
  if (bm == bn && wr == wc){
    int j = frow - kgrp*4;
    if (j >= 0 && j < 4){
      float d = (acc[0][0][j] + acc[1][1][j]) * outscale;
      atomicAdd(&sc[8 + step*2 + z], d);
    }
  }
  if (step == SQN){
    if (bm != bn) fr *= 2.f;                   // off-diag tiles appear twice in ||C||_F^2
    #pragma unroll
    for (int off = 32; off; off >>= 1) fr += __shfl_down(fr, off, 64);
    if (lane == 0) atomicAdd(&sc[8 + 2*(SQN+1) + z], fr);
  }
}

__device__ __forceinline__ float softplusf(float x){
  return (x > 0.f) ? (x + __logf(1.f + __expf(-x))) : __logf(1.f + __expf(x));
}
__device__ __forceinline__ float tanhfastf(float x){
  float e = __expf(2.f * x);
  return 1.f - 2.f/(e + 1.f);
}
__device__ __forceinline__ void abc_from(float pin, float draw, float braw, float craw,
    float alpha, float ginv, float& a_o, float& bu_o, float& c_o){
  float sp = softplusf(draw);
  float av = __expf(-sp * alpha);
  av = fminf(av, 1.f - 1e-4f);
  float bv = tanhfastf(braw);
  float cv = tanhfastf(craw);
  float p = av*av + cv*cv;
  float r = bv*bv;
  float q = av*bv;
  float pr = p - r;
  float disc = pr*pr + 4.f*q*q;
  float lam = 0.5f*(p + r + sqrtf(disc + 1e-12f));
  float sig = sqrtf(lam + 1e-12f);
  float inv = 1.f / fmaxf(sig, 1.f);
  a_o = av * inv;
  c_o = cv * inv;
  bu_o = (bv * inv) * (pin * ginv);
}

// ---- pass1: per-chunk (A,S), 8B/lane loads, 4 n's per thread ----
__global__ __launch_bounds__(256) void k_pass1(
    const unsigned short* __restrict__ P,
    const float* __restrict__ alog, const float* __restrict__ dbias,
    const float* __restrict__ pnb, const float* __restrict__ lgam,
    const float* __restrict__ sc,
    float* __restrict__ Asum, float* __restrict__ Ssum)
{
  const int tid = threadIdx.x;
  const int n0 = tid*4;
  const int ch = blockIdx.x, b = blockIdx.y;
  const float ginv = __expf(lgam[0]) * inv_scale(sc, 0);
  float alpha[4], bd[4], bb[4], bc[4], A[4], S[4];
  #pragma unroll
  for (int j = 0; j < 4; j++){
    alpha[j] = softplusf(alog[n0+j]);
    bd[j] = dbias[n0+j] + pnb[n0+j];
    bb[j] = pnb[N_ + n0+j];
    bc[j] = pnb[2*N_ + n0+j];
    A[j] = 1.f; S[j] = 0.f;
  }
  const unsigned short* Pr = P + (size_t)(b*T_ + ch*TC) * (4*N_);
  #pragma unroll 2
  for (int i = 0; i < TC; i++){
    us4 vp = *(const us4*)(Pr + n0);
    us4 vd = *(const us4*)(Pr + N_ + n0);
    us4 vb = *(const us4*)(Pr + 2*N_ + n0);
    us4 vc = *(const us4*)(Pr + 3*N_ + n0);
    #pragma unroll
    for (int j = 0; j < 4; j++){
      float a, bu, c;
      abc_from(bf2f(vp[j]), bf2f(vd[j]) + bd[j], bf2f(vb[j]) + bb[j], bf2f(vc[j]) + bc[j],
               alpha[j], ginv, a, bu, c);
      S[j] = fmaf(a, S[j], bu);
      A[j] *= a;
    }
    Pr += 4*N_;
  }
  const size_t idx = (size_t)(b*NCH + ch)*N_ + n0;
  #pragma unroll
  for (int j = 0; j < 4; j++){ Asum[idx+j] = A[j]; Ssum[idx+j] = S[j]; }
}

__global__ void k_pass2(const float* __restrict__ Asum, const float* __restrict__ Ssum,
                        const float* __restrict__ z0, float* __restrict__ Zent)
{
  const int n = blockIdx.x*256 + threadIdx.x;
  const int b = blockIdx.y;
  float z = z0[b*N_ + n];
  for (int ch = 0; ch < NCH; ch++){
    const size_t idx = (size_t)(b*NCH + ch)*N_ + n;
    Zent[idx] = z;
    z = fmaf(Asum[idx], z, Ssum[idx]);
  }
}

// ---- pass3: recompute gates, emit y_hat = c * z(before); 8B/lane ----
__global__ __launch_bounds__(256) void k_pass3(
    const unsigned short* __restrict__ P,
    const float* __restrict__ alog, const float* __restrict__ dbias,
    const float* __restrict__ pnb, const float* __restrict__ lgam,
    const float* __restrict__ sc, const float* __restrict__ Zent,
    unsigned short* __restrict__ yh)
{
  const int tid = threadIdx.x;
  const int n0 = tid*4;
  const int ch = blockIdx.x, b = blockIdx.y;
  const float ginv = __expf(lgam[0]) * inv_scale(sc, 0);
  float alpha[4], bd[4], bb[4], bc[4], z[4];
  #pragma unroll
  for (int j = 0; j < 4; j++){
    alpha[j] = softplusf(alog[n0+j]);
    bd[j] = dbias[n0+j] + pnb[n0+j];
    bb[j] = pnb[N_ + n0+j];
    bc[j] = pnb[2*N_ + n0+j];
  }
  const size_t zidx = (size_t)(b*NCH + ch)*N_ + n0;
  #pragma unroll
  for (int j = 0; j < 4; j++) z[j] = Zent[zidx+j];
  const unsigned short* Pr = P + (size_t)(b*T_ + ch*TC) * (4*N_);
  unsigned short* Y = yh + (size_t)(b*T_ + ch*TC)*N_ + n0;
  #pragma unroll 2
  for (int i = 0; i < TC; i++){
    us4 vp = *(const us4*)(Pr + n0);
    us4 vd = *(const us4*)(Pr + N_ + n0);
    us4 vb = *(const us4*)(Pr + 2*N_ + n0);
    us4 vc = *(const us4*)(Pr + 3*N_ + n0);
    us4 ow;
    #pragma unroll
    for (int j = 0; j < 4; j++){
      float a, bu, c;
      abc_from(bf2f(vp[j]), bf2f(vd[j]) + bd[j], bf2f(vb[j]) + bb[j], bf2f(vc[j]) + bc[j],
               alpha[j], ginv, a, bu, c);
      float yv = c * z[j];
      z[j] = fmaf(a, z[j], bu);
      ow[j] = f2bf(yv);
    }
    *(us4*)Y = ow;
    Y += N_;
    Pr += 4*N_;
  }
}

extern "C" void kernel_launch(void* const* d_in, const int* in_sizes, int n_in,
                              void* d_out, int out_size, void* d_ws, size_t ws_size,
                              hipStream_t stream)
{
  const float* u    = (const float*)d_in[0];
  const float* z0   = (const float*)d_in[1];
  const float* Win  = (const float*)d_in[2];
  const float* Wout = (const float*)d_in[3];
  const float* pnw  = (const float*)d_in[4];
  const float* pnb  = (const float*)d_in[5];
  const float* alog = (const float*)d_in[6];
  const float* dbias= (const float*)d_in[7];
  const float* lgam = (const float*)d_in[8];

  char* ws = (char*)d_ws;
  size_t off = 0;
  auto alloc = [&](size_t bytes) -> void* {
    void* p = ws + off;
    off += (bytes + 255) & ~(size_t)255;
    return p;
  };
  float*          sc     = (float*)         alloc(1024);
  unsigned short* u16    = (unsigned short*)alloc((size_t)8192*1024*2);
  unsigned short* Wcat16 = (unsigned short*)alloc((size_t)4096*1024*2);
  unsigned short* Wout16 = (unsigned short*)alloc((size_t)1024*1024*2);
  unsigned short* P16    = (unsigned short*)alloc((size_t)8192*4096*2);
  unsigned short* yh16   = (unsigned short*)alloc((size_t)8192*1024*2);
  unsigned short* Hping  = (unsigned short*)alloc((size_t)2*1024*1024*2);
  unsigned short* Hpong  = (unsigned short*)alloc((size_t)2*1024*1024*2);
  float*          Asum   = (float*)alloc((size_t)B_*NCH*N_*4);
  float*          Ssum   = (float*)alloc((size_t)B_*NCH*N_*4);
  float*          Zent   = (float*)alloc((size_t)B_*NCH*N_*4);

  k_convert_all<<<CONV_BLOCKS, 256, 0, stream>>>(u, Win, pnw, Wout, u16, Wcat16, Wout16, sc);

  // spectral-norm chains: gram (step 0) + SQN squarings (triangular); frob fused in last step
  dim3 gsq(136, 1, 2);
  k_sq<<<gsq, 256, 0, stream>>>(Wcat16, Hping, Wout16, Hping + (size_t)1024*1024, sc, 0);
  unsigned short* hin = Hping;
  unsigned short* hout = Hpong;
  for (int s = 1; s <= SQN; s++){
    k_sq<<<gsq, 256, 0, stream>>>(hin, hout, hin + (size_t)1024*1024, hout + (size_t)1024*1024, sc, s);
    unsigned short* t = hin; hin = hout; hout = t;
  }

  // P = u @ [W_in; pn_w]^T  (bf16 out; inv_scale applied in pass1/pass3)
  dim3 g1(4096/128, 8192/128);
  k_gemm<1><<<g1, 256, 0, stream>>>(u16, Wcat16, P16, 8192, 4096, 1024, sc, -1);

  dim3 gp1(NCH, B_);
  k_pass1<<<gp1, 256, 0, stream>>>(P16, alog, dbias, pnb, lgam, sc, Asum, Ssum);
  dim3 gp2(N_/256, B_);
  k_pass2<<<gp2, 256, 0, stream>>>(Asum, Ssum, z0, Zent);
  k_pass3<<<gp1, 256, 0, stream>>>(P16, alog, dbias, pnb, lgam, sc, Zent, yh16);

  // y = (y_hat @ W_out^T) * inv_scale(sc,1)  (fp32 out)
  dim3 g2(1024/128, 8192/128);
  k_gemm<0><<<g2, 256, 0, stream>>>(yh16, Wout16, d_out, 8192, 1024, 1024, sc, 1);
}

// Round 9
// 290.552 us; speedup vs baseline: 4.1839x; 1.0333x over previous
//
#include <hip/hip_runtime.h>
#include <stdint.h>

#define B_ 4
#define T_ 2048
#define D_ 1024
#define N_ 1024
#define TC 16
#define NCH (T_/TC)
#define SQN 6   // squaring GEMMs after gram; +1 effective doubling via fused Frobenius

typedef __attribute__((ext_vector_type(4))) float f32x4;
typedef __attribute__((ext_vector_type(8))) short bf16x8;
typedef __attribute__((ext_vector_type(4))) unsigned short us4;

__device__ __forceinline__ unsigned short f2bf(float f){
  unsigned int u = __float_as_uint(f);
  return (unsigned short)((u + 0x7fffu + ((u >> 16) & 1u)) >> 16);
}
__device__ __forceinline__ float bf2f(unsigned short h){
  return __uint_as_float(((unsigned int)h) << 16);
}

// inverse spectral scale from trace chain (z=0: W_in, z=1: W_out)
__device__ __forceinline__ float inv_scale(const float* __restrict__ sc, int z){
  float ll = 0.f, w = 1.f, t = 1.f;
  #pragma unroll
  for (int i = 0; i <= SQN; i++){
    t = sc[8 + 2*i + z];
    ll += w * __logf(t);
    w *= 0.5f;
  }
  float F = sc[8 + 2*(SQN+1) + z];
  ll += w * __logf(F / (t*t));
  float sig = fmaxf(__expf(0.5f * ll), 1e-5f);
  return 1.f / fmaxf(sig, 1.f);
}

// ---- fused fp32->bf16 conversion + INTERLEAVE of weight rows + sc zero-init ----
// Wcat16 row (4n+s): s=0 -> W_in[n], s=1..3 -> pn_w[(s-1)*N + n] (delta, b, c).
// => P = u @ Wcat^T has layout [t][n][4]: all 4 gate streams adjacent per n.
#define U4    2097152   // 8192*1024/4
#define WIN4   262144   // 1024*1024/4
#define PNW4   786432   // 3072*1024/4
#define WOUT4  262144
#define CONV_BLOCKS ((U4 + WIN4 + PNW4 + WOUT4 + 255)/256)

__global__ void k_convert_all(const float* __restrict__ u, const float* __restrict__ Win,
                              const float* __restrict__ pnw, const float* __restrict__ Wout,
                              unsigned short* __restrict__ u16, unsigned short* __restrict__ Wcat16,
                              unsigned short* __restrict__ Wout16, float* __restrict__ sc){
  if (blockIdx.x == 0 && threadIdx.x < 64) sc[threadIdx.x] = 0.f;
  long i = (long)blockIdx.x * 256 + threadIdx.x;   // float4 index
  const float* src; long o; size_t didx; unsigned short* dbuf;
  if (i < U4){
    src = u; o = i; dbuf = u16; didx = (size_t)o;
  } else if (i < U4+WIN4){
    o = i - U4; src = Win;
    int n = (int)(o >> 8), c4 = (int)(o & 255);
    dbuf = Wcat16; didx = (size_t)(4*n)*256 + c4;
  } else if (i < U4+WIN4+PNW4){
    o = i - (U4+WIN4); src = pnw;
    int m = (int)(o >> 8), c4 = (int)(o & 255);
    int s = (m >> 10) + 1, n = m & 1023;
    dbuf = Wcat16; didx = (size_t)(4*n + s)*256 + c4;
  } else if (i < U4+WIN4+PNW4+WOUT4){
    o = i - (U4+WIN4+PNW4); src = Wout; dbuf = Wout16; didx = (size_t)o;
  } else return;
  float4 v = ((const float4*)src)[o];
  us4 w;
  w.x = f2bf(v.x); w.y = f2bf(v.y); w.z = f2bf(v.z); w.w = f2bf(v.w);
  ((us4*)dbuf)[didx] = w;
}

__device__ __forceinline__ void load_lds16(const unsigned short* g, unsigned short* l){
  __builtin_amdgcn_global_load_lds((const __attribute__((address_space(1))) void*)g,
                                   (__attribute__((address_space(3))) void*)l, 16, 0, 0);
}

// ---- big GEMM: C[M,N] = (A[M,K] * B[N,K]^T) * (step>=0 ? inv_scale(step) : 1) ----
// 128x128 tile, proven m97-structure; staging addresses hoisted + incremented.
template<int OUTBF16>
__global__ __launch_bounds__(256) void k_gemm(
    const unsigned short* __restrict__ A,
    const unsigned short* __restrict__ Bmat,
    void* __restrict__ C0,
    int M, int N, int K,
    const float* __restrict__ sc, int step)
{
  __shared__ alignas(16) unsigned short As[128*64];
  __shared__ alignas(16) unsigned short Bs[128*64];
  const int tid = threadIdx.x;
  const int wid = tid >> 6;
  const int lane = tid & 63;
  const int bn = blockIdx.x, bm = blockIdx.y;

  char* C = (char*)C0;
  float outscale = (step >= 0) ? inv_scale(sc, step) : 1.f;

  const int wr = wid >> 1, wc = wid & 1;
  const int rg = lane >> 3;
  const int cby = (lane & 7) << 4;
  const int srow0 = wid * 32;
  const int frow = lane & 15;
  const int kgrp = lane >> 4;

  // hoisted staging pointers (advance by 64 elements per K-iter)
  const unsigned short* ap[4];
  const unsigned short* bp[4];
  unsigned short* adst[4];
  unsigned short* bdst[4];
  #pragma unroll
  for (int i = 0; i < 4; i++){
    int r = srow0 + i*8 + rg;
    int cb = cby ^ ((r & 7) << 4);
    ap[i] = A    + (size_t)(bm*128 + r)*K + (cb >> 1);
    bp[i] = Bmat + (size_t)(bn*128 + r)*K + (cb >> 1);
    adst[i] = As + (srow0 + i*8)*64;
    bdst[i] = Bs + (srow0 + i*8)*64;
  }

  // hoisted fragment byte-offsets
  int aoff[4][2], boff[4][2];
  #pragma unroll
  for (int m = 0; m < 4; m++){
    int r = wr*64 + m*16 + frow;
    #pragma unroll
    for (int kk = 0; kk < 2; kk++)
      aoff[m][kk] = r*128 + ((kk*64 + kgrp*16) ^ ((r & 7) << 4));
  }
  #pragma unroll
  for (int n2 = 0; n2 < 4; n2++){
    int r = wc*64 + n2*16 + frow;
    #pragma unroll
    for (int kk = 0; kk < 2; kk++)
      boff[n2][kk] = r*128 + ((kk*64 + kgrp*16) ^ ((r & 7) << 4));
  }

  f32x4 acc[4][4] = {};

  for (int kt = 0; kt < K; kt += 64){
    #pragma unroll
    for (int i = 0; i < 4; i++){
      load_lds16(ap[i], adst[i]);
      load_lds16(bp[i], bdst[i]);
      ap[i] += 64; bp[i] += 64;
    }
    __syncthreads();
    #pragma unroll
    for (int kk = 0; kk < 2; kk++){
      bf16x8 af[4], bfv[4];
      #pragma unroll
      for (int m = 0; m < 4; m++)
        af[m] = *(const bf16x8*)((const char*)As + aoff[m][kk]);
      #pragma unroll
      for (int n2 = 0; n2 < 4; n2++)
        bfv[n2] = *(const bf16x8*)((const char*)Bs + boff[n2][kk]);
      #pragma unroll
      for (int m = 0; m < 4; m++)
        #pragma unroll
        for (int n2 = 0; n2 < 4; n2++)
          acc[m][n2] = __builtin_amdgcn_mfma_f32_16x16x32_bf16(af[m], bfv[n2], acc[m][n2], 0, 0, 0);
    }
    __syncthreads();
  }

  const int row0 = bm*128 + wr*64;
  const int col0 = bn*128 + wc*64 + frow;
  #pragma unroll
  for (int m = 0; m < 4; m++){
    #pragma unroll
    for (int n2 = 0; n2 < 4; n2++){
      const int col = col0 + n2*16;
      const int rb = row0 + m*16 + kgrp*4;
      #pragma unroll
      for (int j = 0; j < 4; j++){
        float v = acc[m][n2][j] * outscale;
        if (OUTBF16) ((unsigned short*)C)[(size_t)(rb + j)*N + col] = f2bf(v);
        else         ((float*)C)[(size_t)(rb + j)*N + col] = v;
      }
    }
  }
}

// ---- triangular squaring-chain GEMM (C = X*X^T symmetric, upper tiles only) ----
// step 0, z=0 reads W_in rows through the interleaved Wcat (row stride 4096).
__global__ __launch_bounds__(256) void k_sq(
    const unsigned short* __restrict__ A0, unsigned short* __restrict__ C0,
    const unsigned short* __restrict__ A1, unsigned short* __restrict__ C1,
    float* __restrict__ sc, int step)
{
  __shared__ alignas(16) unsigned short As0[64*128], Bs0[64*128];
  __shared__ alignas(16) unsigned short As1[64*128], Bs1[64*128];
  const int tid = threadIdx.x;
  const int wid = tid >> 6;
  const int lane = tid & 63;
  const int z = blockIdx.z;

  int x = blockIdx.x, bm = 0;
  while (x >= 16 - bm){ x -= 16 - bm; bm++; }
  const int bn = bm + x;

  const unsigned short* A = z ? A1 : A0;
  unsigned short* C = z ? C1 : C0;
  const size_t rs = (step == 0 && z == 0) ? 4096 : 1024;   // interleaved W_in stride
  float outscale = 1.f;
  if (step > 0){ float t = sc[8 + (step-1)*2 + z]; outscale = 1.f/(t*t); }

  const int wr = wid >> 1, wc = wid & 1;
  const int frow = lane & 15;
  const int kgrp = lane >> 4;

  const int srl = lane >> 4;
  const int sgr = lane & 15;
  const int swzr = wid*4 + srl;
  const int scol_e = ((sgr ^ swzr) << 3);

  const size_t Arow = (size_t)bm * 64;
  const size_t Brow = (size_t)bn * 64;

  f32x4 acc[2][2] = {};

  auto stage = [&](unsigned short* as, unsigned short* bs, int t){
    const int kt = t * 128;
    #pragma unroll
    for (int i = 0; i < 4; i++){
      int r = i*16 + wid*4 + srl;
      load_lds16(A + (Arow + r)*rs + kt + scol_e, as + (i*16 + wid*4)*128);
      load_lds16(A + (Brow + r)*rs + kt + scol_e, bs + (i*16 + wid*4)*128);
    }
  };

  auto compute = [&](const unsigned short* as, const unsigned short* bs){
    #pragma unroll
    for (int ks = 0; ks < 4; ks++){
      const int kb = ks*64 + kgrp*16;
      bf16x8 af[2], bfv[2];
      #pragma unroll
      for (int m = 0; m < 2; m++){
        int r = wr*32 + m*16 + frow;
        af[m] = *(const bf16x8*)((const char*)as + r*256 + (kb ^ (frow << 4)));
      }
      #pragma unroll
      for (int n2 = 0; n2 < 2; n2++){
        int r = wc*32 + n2*16 + frow;
        bfv[n2] = *(const bf16x8*)((const char*)bs + r*256 + (kb ^ (frow << 4)));
      }
      #pragma unroll
      for (int m = 0; m < 2; m++)
        #pragma unroll
        for (int n2 = 0; n2 < 2; n2++)
          acc[m][n2] = __builtin_amdgcn_mfma_f32_16x16x32_bf16(af[m], bfv[n2], acc[m][n2], 0, 0, 0);
    }
  };

  stage(As0, Bs0, 0);
  __syncthreads();
  for (int t2 = 0; t2 < 8; t2 += 2){
    if (t2 + 1 < 8) stage(As1, Bs1, t2 + 1);
    compute(As0, Bs0);
    __syncthreads();
    if (t2 + 2 < 8) stage(As0, Bs0, t2 + 2);
    compute(As1, Bs1);
    __syncthreads();
  }

  const int row0 = bm*64 + wr*32;
  const int col0 = bn*64 + wc*32 + frow;
  float fr = 0.f;
  #pragma unroll
  for (int m = 0; m < 2; m++){
    #pragma unroll
    for (int n2 = 0; n2 < 2; n2++){
      const int col = col0 + n2*16;
      const int rb = row0 + m*16 + kgrp*4;
      us4 tw;
      #pragma unroll
      for (int j = 0; j < 4; j++){
        float v = acc[m][n2][j] * outscale;
        unsigned short h = f2bf(v);
        C[(size_t)(rb + j)*1024 + col] = h;
        tw[j] = h;
        fr += v*v;
      }
      if (bm != bn)
        *(us4*)(C + (size_t)col*1024 + rb) = tw;
    }
  }
  if (bm == bn && wr == wc){
    int j = frow - kgrp*4;
    if (j >= 0 && j < 4){
      float d = (acc[0][0][j] + acc[1][1][j]) * outscale;
      atomicAdd(&sc[8 + step*2 + z], d);
    }
  }
  if (step == SQN){
    if (bm != bn) fr *= 2.f;
    #pragma unroll
    for (int off = 32; off; off >>= 1) fr += __shfl_down(fr, off, 64);
    if (lane == 0) atomicAdd(&sc[8 + 2*(SQN+1) + z], fr);
  }
}

__device__ __forceinline__ float softplusf(float x){
  return (x > 0.f) ? (x + __logf(1.f + __expf(-x))) : __logf(1.f + __expf(x));
}
__device__ __forceinline__ float tanhfastf(float x){
  float e = __expf(2.f * x);
  return 1.f - 2.f/(e + 1.f);
}
__device__ __forceinline__ void abc_from(float pin, float draw, float braw, float craw,
    float alpha, float ginv, float& a_o, float& bu_o, float& c_o){
  float sp = softplusf(draw);
  float av = __expf(-sp * alpha);
  av = fminf(av, 1.f - 1e-4f);
  float bv = tanhfastf(braw);
  float cv = tanhfastf(craw);
  float p = av*av + cv*cv;
  float r = bv*bv;
  float q = av*bv;
  float pr = p - r;
  float disc = pr*pr + 4.f*q*q;
  float lam = 0.5f*(p + r + sqrtf(disc + 1e-12f));
  float inv = fminf(rsqrtf(lam + 1e-12f), 1.f);   // == 1/max(sqrt(lam+eps),1)
  a_o = av * inv;
  c_o = cv * inv;
  bu_o = (bv * inv) * (pin * ginv);
}

// ---- pass1: per-chunk (A,S); interleaved P -> 2 x b128 loads per (t, 4n) ----
__global__ __launch_bounds__(256) void k_pass1(
    const unsigned short* __restrict__ P,
    const float* __restrict__ alog, const float* __restrict__ dbias,
    const float* __restrict__ pnb, const float* __restrict__ lgam,
    const float* __restrict__ sc,
    float* __restrict__ Asum, float* __restrict__ Ssum)
{
  const int tid = threadIdx.x;
  const int n0 = tid*4;
  const int ch = blockIdx.x, b = blockIdx.y;
  const float ginv = __expf(lgam[0]) * inv_scale(sc, 0);
  float alpha[4], bd[4], bb[4], bc[4], A[4], S[4];
  #pragma unroll
  for (int j = 0; j < 4; j++){
    alpha[j] = softplusf(alog[n0+j]);
    bd[j] = dbias[n0+j] + pnb[n0+j];
    bb[j] = pnb[N_ + n0+j];
    bc[j] = pnb[2*N_ + n0+j];
    A[j] = 1.f; S[j] = 0.f;
  }
  const unsigned short* Pr = P + (size_t)(b*T_ + ch*TC) * 4096 + 4*n0;
  #pragma unroll 2
  for (int i = 0; i < TC; i++){
    bf16x8 e0 = *(const bf16x8*)Pr;
    bf16x8 e1 = *(const bf16x8*)(Pr + 8);
    #pragma unroll
    for (int j = 0; j < 4; j++){
      const bf16x8& e = (j < 2) ? e0 : e1;
      const int o = (j & 1)*4;
      float a, bu, c;
      abc_from(bf2f((unsigned short)e[o]),   bf2f((unsigned short)e[o+1]) + bd[j],
               bf2f((unsigned short)e[o+2]) + bb[j], bf2f((unsigned short)e[o+3]) + bc[j],
               alpha[j], ginv, a, bu, c);
      S[j] = fmaf(a, S[j], bu);
      A[j] *= a;
    }
    Pr += 4096;
  }
  const size_t idx = (size_t)(b*NCH + ch)*N_ + n0;
  #pragma unroll
  for (int j = 0; j < 4; j++){ Asum[idx+j] = A[j]; Ssum[idx+j] = S[j]; }
}

__global__ void k_pass2(const float* __restrict__ Asum, const float* __restrict__ Ssum,
                        const float* __restrict__ z0, float* __restrict__ Zent)
{
  const int n = blockIdx.x*256 + threadIdx.x;
  const int b = blockIdx.y;
  float z = z0[b*N_ + n];
  for (int ch = 0; ch < NCH; ch++){
    const size_t idx = (size_t)(b*NCH + ch)*N_ + n;
    Zent[idx] = z;
    z = fmaf(Asum[idx], z, Ssum[idx]);
  }
}

// ---- pass3: recompute gates, emit y_hat = c * z(before); interleaved P ----
__global__ __launch_bounds__(256) void k_pass3(
    const unsigned short* __restrict__ P,
    const float* __restrict__ alog, const float* __restrict__ dbias,
    const float* __restrict__ pnb, const float* __restrict__ lgam,
    const float* __restrict__ sc, const float* __restrict__ Zent,
    unsigned short* __restrict__ yh)
{
  const int tid = threadIdx.x;
  const int n0 = tid*4;
  const int ch = blockIdx.x, b = blockIdx.y;
  const float ginv = __expf(lgam[0]) * inv_scale(sc, 0);
  float alpha[4], bd[4], bb[4], bc[4], z[4];
  #pragma unroll
  for (int j = 0; j < 4; j++){
    alpha[j] = softplusf(alog[n0+j]);
    bd[j] = dbias[n0+j] + pnb[n0+j];
    bb[j] = pnb[N_ + n0+j];
    bc[j] = pnb[2*N_ + n0+j];
  }
  const size_t zidx = (size_t)(b*NCH + ch)*N_ + n0;
  #pragma unroll
  for (int j = 0; j < 4; j++) z[j] = Zent[zidx+j];
  const unsigned short* Pr = P + (size_t)(b*T_ + ch*TC) * 4096 + 4*n0;
  unsigned short* Y = yh + (size_t)(b*T_ + ch*TC)*N_ + n0;
  #pragma unroll 2
  for (int i = 0; i < TC; i++){
    bf16x8 e0 = *(const bf16x8*)Pr;
    bf16x8 e1 = *(const bf16x8*)(Pr + 8);
    us4 ow;
    #pragma unroll
    for (int j = 0; j < 4; j++){
      const bf16x8& e = (j < 2) ? e0 : e1;
      const int o = (j & 1)*4;
      float a, bu, c;
      abc_from(bf2f((unsigned short)e[o]),   bf2f((unsigned short)e[o+1]) + bd[j],
               bf2f((unsigned short)e[o+2]) + bb[j], bf2f((unsigned short)e[o+3]) + bc[j],
               alpha[j], ginv, a, bu, c);
      float yv = c * z[j];
      z[j] = fmaf(a, z[j], bu);
      ow[j] = f2bf(yv);
    }
    *(us4*)Y = ow;
    Y += N_;
    Pr += 4096;
  }
}

extern "C" void kernel_launch(void* const* d_in, const int* in_sizes, int n_in,
                              void* d_out, int out_size, void* d_ws, size_t ws_size,
                              hipStream_t stream)
{
  const float* u    = (const float*)d_in[0];
  const float* z0   = (const float*)d_in[1];
  const float* Win  = (const float*)d_in[2];
  const float* Wout = (const float*)d_in[3];
  const float* pnw  = (const float*)d_in[4];
  const float* pnb  = (const float*)d_in[5];
  const float* alog = (const float*)d_in[6];
  const float* dbias= (const float*)d_in[7];
  const float* lgam = (const float*)d_in[8];

  char* ws = (char*)d_ws;
  size_t off = 0;
  auto alloc = [&](size_t bytes) -> void* {
    void* p = ws + off;
    off += (bytes + 255) & ~(size_t)255;
    return p;
  };
  float*          sc     = (float*)         alloc(1024);
  unsigned short* u16    = (unsigned short*)alloc((size_t)8192*1024*2);
  unsigned short* Wcat16 = (unsigned short*)alloc((size_t)4096*1024*2);
  unsigned short* Wout16 = (unsigned short*)alloc((size_t)1024*1024*2);
  unsigned short* P16    = (unsigned short*)alloc((size_t)8192*4096*2);
  unsigned short* yh16   = (unsigned short*)alloc((size_t)8192*1024*2);
  unsigned short* Hping  = (unsigned short*)alloc((size_t)2*1024*1024*2);
  unsigned short* Hpong  = (unsigned short*)alloc((size_t)2*1024*1024*2);
  float*          Asum   = (float*)alloc((size_t)B_*NCH*N_*4);
  float*          Ssum   = (float*)alloc((size_t)B_*NCH*N_*4);
  float*          Zent   = (float*)alloc((size_t)B_*NCH*N_*4);

  k_convert_all<<<CONV_BLOCKS, 256, 0, stream>>>(u, Win, pnw, Wout, u16, Wcat16, Wout16, sc);

  // spectral-norm chains: gram (step 0) + SQN squarings (triangular); frob fused in last step
  dim3 gsq(136, 1, 2);
  k_sq<<<gsq, 256, 0, stream>>>(Wcat16, Hping, Wout16, Hping + (size_t)1024*1024, sc, 0);
  unsigned short* hin = Hping;
  unsigned short* hout = Hpong;
  for (int s = 1; s <= SQN; s++){
    k_sq<<<gsq, 256, 0, stream>>>(hin, hout, hin + (size_t)1024*1024, hout + (size_t)1024*1024, sc, s);
    unsigned short* t = hin; hin = hout; hout = t;
  }

  // P = u @ Wcat^T  (bf16 out, interleaved columns; inv_scale applied in pass1/pass3)
  dim3 g1(4096/128, 8192/128);
  k_gemm<1><<<g1, 256, 0, stream>>>(u16, Wcat16, P16, 8192, 4096, 1024, sc, -1);

  dim3 gp1(NCH, B_);
  k_pass1<<<gp1, 256, 0, stream>>>(P16, alog, dbias, pnb, lgam, sc, Asum, Ssum);
  dim3 gp2(N_/256, B_);
  k_pass2<<<gp2, 256, 0, stream>>>(Asum, Ssum, z0, Zent);
  k_pass3<<<gp1, 256, 0, stream>>>(P16, alog, dbias, pnb, lgam, sc, Zent, yh16);

  // y = (y_hat @ W_out^T) * inv_scale(sc,1)  (fp32 out)
  dim3 g2(1024/128, 8192/128);
  k_gemm<0><<<g2, 256, 0, stream>>>(yh16, Wout16, d_out, 8192, 1024, 1024, sc, 1);
}

// Round 10
// 290.343 us; speedup vs baseline: 4.1869x; 1.0007x over previous
//
#include <hip/hip_runtime.h>
#include <stdint.h>

#define B_ 4
#define T_ 2048
#define D_ 1024
#define N_ 1024
#define TC 16
#define NCH (T_/TC)
#define SQN 6   // squaring GEMMs after gram; +1 effective doubling via fused Frobenius

typedef __attribute__((ext_vector_type(4))) float f32x4;
typedef __attribute__((ext_vector_type(8))) short bf16x8;
typedef __attribute__((ext_vector_type(4))) unsigned short us4;

__device__ __forceinline__ unsigned short f2bf(float f){
  unsigned int u = __float_as_uint(f);
  return (unsigned short)((u + 0x7fffu + ((u >> 16) & 1u)) >> 16);
}
__device__ __forceinline__ float bf2f(unsigned short h){
  return __uint_as_float(((unsigned int)h) << 16);
}

// inverse spectral scale from trace chain (z=0: W_in, z=1: W_out)
__device__ __forceinline__ float inv_scale(const float* __restrict__ sc, int z){
  float ll = 0.f, w = 1.f, t = 1.f;
  #pragma unroll
  for (int i = 0; i <= SQN; i++){
    t = sc[8 + 2*i + z];
    ll += w * __logf(t);
    w *= 0.5f;
  }
  float F = sc[8 + 2*(SQN+1) + z];
  ll += w * __logf(F / (t*t));
  float sig = fmaxf(__expf(0.5f * ll), 1e-5f);
  return 1.f / fmaxf(sig, 1.f);
}

__device__ __forceinline__ float softplusf(float x){
  return (x > 0.f) ? (x + __logf(1.f + __expf(-x))) : __logf(1.f + __expf(x));
}
__device__ __forceinline__ float tanhfastf(float x){
  float e = __expf(2.f * x);
  return 1.f - 2.f/(e + 1.f);
}
__device__ __forceinline__ void abc_from(float pin, float draw, float braw, float craw,
    float alpha, float ginv, float& a_o, float& bu_o, float& c_o){
  float sp = softplusf(draw);
  float av = __expf(-sp * alpha);
  av = fminf(av, 1.f - 1e-4f);
  float bv = tanhfastf(braw);
  float cv = tanhfastf(craw);
  float p = av*av + cv*cv;
  float r = bv*bv;
  float q = av*bv;
  float pr = p - r;
  float disc = pr*pr + 4.f*q*q;
  float lam = 0.5f*(p + r + sqrtf(disc + 1e-12f));
  float inv = fminf(rsqrtf(lam + 1e-12f), 1.f);
  a_o = av * inv;
  c_o = cv * inv;
  bu_o = (bv * inv) * (pin * ginv);
}

// ---- fused fp32->bf16 conversion + INTERLEAVE of weight rows + sc zero-init ----
// Wcat16 row (4n+s): s=0 -> W_in[n], s=1..3 -> pn_w[(s-1)*N + n] (delta, b, c).
#define U4    2097152
#define WIN4   262144
#define PNW4   786432
#define WOUT4  262144
#define CONV_BLOCKS ((U4 + WIN4 + PNW4 + WOUT4 + 255)/256)

__global__ void k_convert_all(const float* __restrict__ u, const float* __restrict__ Win,
                              const float* __restrict__ pnw, const float* __restrict__ Wout,
                              unsigned short* __restrict__ u16, unsigned short* __restrict__ Wcat16,
                              unsigned short* __restrict__ Wout16, float* __restrict__ sc){
  if (blockIdx.x == 0 && threadIdx.x < 64) sc[threadIdx.x] = 0.f;
  long i = (long)blockIdx.x * 256 + threadIdx.x;
  const float* src; long o; size_t didx; unsigned short* dbuf;
  if (i < U4){
    src = u; o = i; dbuf = u16; didx = (size_t)o;
  } else if (i < U4+WIN4){
    o = i - U4; src = Win;
    int n = (int)(o >> 8), c4 = (int)(o & 255);
    dbuf = Wcat16; didx = (size_t)(4*n)*256 + c4;
  } else if (i < U4+WIN4+PNW4){
    o = i - (U4+WIN4); src = pnw;
    int m = (int)(o >> 8), c4 = (int)(o & 255);
    int s = (m >> 10) + 1, n = m & 1023;
    dbuf = Wcat16; didx = (size_t)(4*n + s)*256 + c4;
  } else if (i < U4+WIN4+PNW4+WOUT4){
    o = i - (U4+WIN4+PNW4); src = Wout; dbuf = Wout16; didx = (size_t)o;
  } else return;
  float4 v = ((const float4*)src)[o];
  us4 w;
  w.x = f2bf(v.x); w.y = f2bf(v.y); w.z = f2bf(v.z); w.w = f2bf(v.w);
  ((us4*)dbuf)[didx] = w;
}

__device__ __forceinline__ void load_lds16(const unsigned short* g, unsigned short* l){
  __builtin_amdgcn_global_load_lds((const __attribute__((address_space(1))) void*)g,
                                   (__attribute__((address_space(3))) void*)l, 16, 0, 0);
}

// ==== gated P-GEMM: computes u @ Wcat^T in 128x128 tiles, then applies the gate
// math IN THE EPILOGUE (quad transpose -> fp32 gates -> G1/G2 stores) and reduces
// per-chunk (A,S) in-register (ordered 16-lane xor butterfly) -> Asum/Ssum.
// P is never materialized; pass1 & pass2 kernels eliminated.
__global__ __launch_bounds__(256) void k_pgemm(
    const unsigned short* __restrict__ A,
    const unsigned short* __restrict__ Bmat,
    const float* __restrict__ alog, const float* __restrict__ dbias,
    const float* __restrict__ pnb, const float* __restrict__ lgam,
    const float* __restrict__ sc,
    unsigned int* __restrict__ G1,   // [t][n] packed (a, c) bf16
    float* __restrict__ G2,          // [t][n] bu fp32
    float* __restrict__ Asum, float* __restrict__ Ssum)
{
  __shared__ alignas(16) unsigned short As[128*64];
  __shared__ alignas(16) unsigned short Bs[128*64];
  const int tid = threadIdx.x;
  const int wid = tid >> 6;
  const int lane = tid & 63;
  const int bn = blockIdx.x, bm = blockIdx.y;
  const int K = 1024;

  const int wr = wid >> 1, wc = wid & 1;
  const int rg = lane >> 3;
  const int cby = (lane & 7) << 4;
  const int srow0 = wid * 32;
  const int frow = lane & 15;
  const int kgrp = lane >> 4;

  const unsigned short* ap[4];
  const unsigned short* bp[4];
  unsigned short* adst[4];
  unsigned short* bdst[4];
  #pragma unroll
  for (int i = 0; i < 4; i++){
    int r = srow0 + i*8 + rg;
    int cb = cby ^ ((r & 7) << 4);
    ap[i] = A    + (size_t)(bm*128 + r)*K + (cb >> 1);
    bp[i] = Bmat + (size_t)(bn*128 + r)*K + (cb >> 1);
    adst[i] = As + (srow0 + i*8)*64;
    bdst[i] = Bs + (srow0 + i*8)*64;
  }
  int aoff[4][2], boff[4][2];
  #pragma unroll
  for (int m = 0; m < 4; m++){
    int r = wr*64 + m*16 + frow;
    #pragma unroll
    for (int kk = 0; kk < 2; kk++)
      aoff[m][kk] = r*128 + ((kk*64 + kgrp*16) ^ ((r & 7) << 4));
  }
  #pragma unroll
  for (int n2 = 0; n2 < 4; n2++){
    int r = wc*64 + n2*16 + frow;
    #pragma unroll
    for (int kk = 0; kk < 2; kk++)
      boff[n2][kk] = r*128 + ((kk*64 + kgrp*16) ^ ((r & 7) << 4));
  }

  f32x4 acc[4][4] = {};

  for (int kt = 0; kt < K; kt += 64){
    #pragma unroll
    for (int i = 0; i < 4; i++){
      load_lds16(ap[i], adst[i]);
      load_lds16(bp[i], bdst[i]);
      ap[i] += 64; bp[i] += 64;
    }
    __syncthreads();
    #pragma unroll
    for (int kk = 0; kk < 2; kk++){
      bf16x8 af[4], bfv[4];
      #pragma unroll
      for (int m = 0; m < 4; m++)
        af[m] = *(const bf16x8*)((const char*)As + aoff[m][kk]);
      #pragma unroll
      for (int n2 = 0; n2 < 4; n2++)
        bfv[n2] = *(const bf16x8*)((const char*)Bs + boff[n2][kk]);
      #pragma unroll
      for (int m = 0; m < 4; m++)
        #pragma unroll
        for (int n2 = 0; n2 < 4; n2++)
          acc[m][n2] = __builtin_amdgcn_mfma_f32_16x16x32_bf16(af[m], bfv[n2], acc[m][n2], 0, 0, 0);
    }
    __syncthreads();
  }

  // ===== gated epilogue =====
  const int q = (lane >> 2) & 3;   // n sub-index within quad group
  const int s = lane & 3;          // stream / element index
  const bool sb0 = (lane & 1) != 0;
  const bool sb1 = (lane & 2) != 0;
  const float ginv = __expf(lgam[0]) * inv_scale(sc, 0);

  float alpP[4], bdP[4], bbP[4], bcP[4];
  #pragma unroll
  for (int n2 = 0; n2 < 4; n2++){
    int n = bn*32 + wc*16 + n2*4 + q;
    alpP[n2] = softplusf(alog[n]);
    bdP[n2] = dbias[n] + pnb[n];
    bbP[n2] = pnb[N_ + n];
    bcP[n2] = pnb[2*N_ + n];
  }

  #pragma unroll
  for (int m = 0; m < 4; m++){
    #pragma unroll
    for (int n2 = 0; n2 < 4; n2++){
      f32x4 v = acc[m][n2];
      // quad 4x4 transpose: M[s][j] -> lane s holds all streams of element j==s
      { float x = sb0 ? v[0] : v[1]; float y = __shfl_xor(x, 1, 64); if (sb0) v[0] = y; else v[1] = y; }
      { float x = sb0 ? v[2] : v[3]; float y = __shfl_xor(x, 1, 64); if (sb0) v[2] = y; else v[3] = y; }
      { float x = sb1 ? v[0] : v[2]; float y = __shfl_xor(x, 2, 64); if (sb1) v[0] = y; else v[2] = y; }
      { float x = sb1 ? v[1] : v[3]; float y = __shfl_xor(x, 2, 64); if (sb1) v[1] = y; else v[3] = y; }
      // gates in fp32
      float a, bu, c;
      abc_from(v[0], v[1] + bdP[n2], v[2] + bbP[n2], v[3] + bcP[n2], alpP[n2], ginv, a, bu, c);
      const int row = bm*128 + wr*64 + m*16 + kgrp*4 + s;
      const int n = bn*32 + wc*16 + n2*4 + q;
      G1[(size_t)row*N_ + n] = (unsigned int)f2bf(a) | ((unsigned int)f2bf(c) << 16);
      G2[(size_t)row*N_ + n] = bu;
      // ordered chunk reduce over t = kgrp*4 + s (lane bits {0,1,4,5}), LSB-first
      float Ar = a, Sr = bu;
      { float Ap = __shfl_xor(Ar,1,64), Sp = __shfl_xor(Sr,1,64);
        if (lane & 1){ Sr = fmaf(Ar, Sp, Sr); } else { Sr = fmaf(Ap, Sr, Sp); } Ar *= Ap; }
      { float Ap = __shfl_xor(Ar,2,64), Sp = __shfl_xor(Sr,2,64);
        if (lane & 2){ Sr = fmaf(Ar, Sp, Sr); } else { Sr = fmaf(Ap, Sr, Sp); } Ar *= Ap; }
      { float Ap = __shfl_xor(Ar,16,64), Sp = __shfl_xor(Sr,16,64);
        if (lane & 16){ Sr = fmaf(Ar, Sp, Sr); } else { Sr = fmaf(Ap, Sr, Sp); } Ar *= Ap; }
      { float Ap = __shfl_xor(Ar,32,64), Sp = __shfl_xor(Sr,32,64);
        if (lane & 32){ Sr = fmaf(Ar, Sp, Sr); } else { Sr = fmaf(Ap, Sr, Sp); } Ar *= Ap; }
      if ((lane & 0x33) == 0){
        const size_t ci = (size_t)(row >> 4)*N_ + n;   // kgrp==0, s==0 -> row>>4 = chunk
        Asum[ci] = Ar; Ssum[ci] = Sr;
      }
    }
  }
}

// ---- out-GEMM: C[M,N] = (A[M,K] * B[N,K]^T) * inv_scale(step)  (128x128, m97) ----
__global__ __launch_bounds__(256) void k_gemm(
    const unsigned short* __restrict__ A,
    const unsigned short* __restrict__ Bmat,
    float* __restrict__ C,
    int M, int N, int K,
    const float* __restrict__ sc, int step)
{
  __shared__ alignas(16) unsigned short As[128*64];
  __shared__ alignas(16) unsigned short Bs[128*64];
  const int tid = threadIdx.x;
  const int wid = tid >> 6;
  const int lane = tid & 63;
  const int bn = blockIdx.x, bm = blockIdx.y;

  float outscale = (step >= 0) ? inv_scale(sc, step) : 1.f;

  const int wr = wid >> 1, wc = wid & 1;
  const int rg = lane >> 3;
  const int cby = (lane & 7) << 4;
  const int srow0 = wid * 32;
  const int frow = lane & 15;
  const int kgrp = lane >> 4;

  const unsigned short* ap[4];
  const unsigned short* bp[4];
  unsigned short* adst[4];
  unsigned short* bdst[4];
  #pragma unroll
  for (int i = 0; i < 4; i++){
    int r = srow0 + i*8 + rg;
    int cb = cby ^ ((r & 7) << 4);
    ap[i] = A    + (size_t)(bm*128 + r)*K + (cb >> 1);
    bp[i] = Bmat + (size_t)(bn*128 + r)*K + (cb >> 1);
    adst[i] = As + (srow0 + i*8)*64;
    bdst[i] = Bs + (srow0 + i*8)*64;
  }
  int aoff[4][2], boff[4][2];
  #pragma unroll
  for (int m = 0; m < 4; m++){
    int r = wr*64 + m*16 + frow;
    #pragma unroll
    for (int kk = 0; kk < 2; kk++)
      aoff[m][kk] = r*128 + ((kk*64 + kgrp*16) ^ ((r & 7) << 4));
  }
  #pragma unroll
  for (int n2 = 0; n2 < 4; n2++){
    int r = wc*64 + n2*16 + frow;
    #pragma unroll
    for (int kk = 0; kk < 2; kk++)
      boff[n2][kk] = r*128 + ((kk*64 + kgrp*16) ^ ((r & 7) << 4));
  }

  f32x4 acc[4][4] = {};

  for (int kt = 0; kt < K; kt += 64){
    #pragma unroll
    for (int i = 0; i < 4; i++){
      load_lds16(ap[i], adst[i]);
      load_lds16(bp[i], bdst[i]);
      ap[i] += 64; bp[i] += 64;
    }
    __syncthreads();
    #pragma unroll
    for (int kk = 0; kk < 2; kk++){
      bf16x8 af[4], bfv[4];
      #pragma unroll
      for (int m = 0; m < 4; m++)
        af[m] = *(const bf16x8*)((const char*)As + aoff[m][kk]);
      #pragma unroll
      for (int n2 = 0; n2 < 4; n2++)
        bfv[n2] = *(const bf16x8*)((const char*)Bs + boff[n2][kk]);
      #pragma unroll
      for (int m = 0; m < 4; m++)
        #pragma unroll
        for (int n2 = 0; n2 < 4; n2++)
          acc[m][n2] = __builtin_amdgcn_mfma_f32_16x16x32_bf16(af[m], bfv[n2], acc[m][n2], 0, 0, 0);
    }
    __syncthreads();
  }

  const int row0 = bm*128 + wr*64;
  const int col0 = bn*128 + wc*64 + frow;
  #pragma unroll
  for (int m = 0; m < 4; m++){
    #pragma unroll
    for (int n2 = 0; n2 < 4; n2++){
      const int col = col0 + n2*16;
      const int rb = row0 + m*16 + kgrp*4;
      #pragma unroll
      for (int j = 0; j < 4; j++)
        C[(size_t)(rb + j)*N + col] = acc[m][n2][j] * outscale;
    }
  }
}

// ---- triangular squaring-chain GEMM (C = X*X^T symmetric, upper tiles only) ----
__global__ __launch_bounds__(256) void k_sq(
    const unsigned short* __restrict__ A0, unsigned short* __restrict__ C0,
    const unsigned short* __restrict__ A1, unsigned short* __restrict__ C1,
    float* __restrict__ sc, int step)
{
  __shared__ alignas(16) unsigned short As0[64*128], Bs0[64*128];
  __shared__ alignas(16) unsigned short As1[64*128], Bs1[64*128];
  const int tid = threadIdx.x;
  const int wid = tid >> 6;
  const int lane = tid & 63;
  const int z = blockIdx.z;

  int x = blockIdx.x, bm = 0;
  while (x >= 16 - bm){ x -= 16 - bm; bm++; }
  const int bn = bm + x;

  const unsigned short* A = z ? A1 : A0;
  unsigned short* C = z ? C1 : C0;
  const size_t rs = (step == 0 && z == 0) ? 4096 : 1024;
  float outscale = 1.f;
  if (step > 0){ float t = sc[8 + (step-1)*2 + z]; outscale = 1.f/(t*t); }

  const int wr = wid >> 1, wc = wid & 1;
  const int frow = lane & 15;
  const int kgrp = lane >> 4;

  const int srl = lane >> 4;
  const int sgr = lane & 15;
  const int swzr = wid*4 + srl;
  const int scol_e = ((sgr ^ swzr) << 3);

  const size_t Arow = (size_t)bm * 64;
  const size_t Brow = (size_t)bn * 64;

  f32x4 acc[2][2] = {};

  auto stage = [&](unsigned short* as, unsigned short* bs, int t){
    const int kt = t * 128;
    #pragma unroll
    for (int i = 0; i < 4; i++){
      int r = i*16 + wid*4 + srl;
      load_lds16(A + (Arow + r)*rs + kt + scol_e, as + (i*16 + wid*4)*128);
      load_lds16(A + (Brow + r)*rs + kt + scol_e, bs + (i*16 + wid*4)*128);
    }
  };

  auto compute = [&](const unsigned short* as, const unsigned short* bs){
    #pragma unroll
    for (int ks = 0; ks < 4; ks++){
      const int kb = ks*64 + kgrp*16;
      bf16x8 af[2], bfv[2];
      #pragma unroll
      for (int m = 0; m < 2; m++){
        int r = wr*32 + m*16 + frow;
        af[m] = *(const bf16x8*)((const char*)as + r*256 + (kb ^ (frow << 4)));
      }
      #pragma unroll
      for (int n2 = 0; n2 < 2; n2++){
        int r = wc*32 + n2*16 + frow;
        bfv[n2] = *(const bf16x8*)((const char*)bs + r*256 + (kb ^ (frow << 4)));
      }
      #pragma unroll
      for (int m = 0; m < 2; m++)
        #pragma unroll
        for (int n2 = 0; n2 < 2; n2++)
          acc[m][n2] = __builtin_amdgcn_mfma_f32_16x16x32_bf16(af[m], bfv[n2], acc[m][n2], 0, 0, 0);
    }
  };

  stage(As0, Bs0, 0);
  __syncthreads();
  for (int t2 = 0; t2 < 8; t2 += 2){
    if (t2 + 1 < 8) stage(As1, Bs1, t2 + 1);
    compute(As0, Bs0);
    __syncthreads();
    if (t2 + 2 < 8) stage(As0, Bs0, t2 + 2);
    compute(As1, Bs1);
    __syncthreads();
  }

  const int row0 = bm*64 + wr*32;
  const int col0 = bn*64 + wc*32 + frow;
  float fr = 0.f;
  #pragma unroll
  for (int m = 0; m < 2; m++){
    #pragma unroll
    for (int n2 = 0; n2 < 2; n2++){
      const int col = col0 + n2*16;
      const int rb = row0 + m*16 + kgrp*4;
      us4 tw;
      #pragma unroll
      for (int j = 0; j < 4; j++){
        float v = acc[m][n2][j] * outscale;
        unsigned short h = f2bf(v);
        C[(size_t)(rb + j)*1024 + col] = h;
        tw[j] = h;
        fr += v*v;
      }
      if (bm != bn)
        *(us4*)(C + (size_t)col*1024 + rb) = tw;
    }
  }
  if (bm == bn && wr == wc){
    int j = frow - kgrp*4;
    if (j >= 0 && j < 4){
      float d = (acc[0][0][j] + acc[1][1][j]) * outscale;
      atomicAdd(&sc[8 + step*2 + z], d);
    }
  }
  if (step == SQN){
    if (bm != bn) fr *= 2.f;
    #pragma unroll
    for (int off = 32; off; off >>= 1) fr += __shfl_down(fr, off, 64);
    if (lane == 0) atomicAdd(&sc[8 + 2*(SQN+1) + z], fr);
  }
}

// ---- k_scan: self prefix-scan over Asum/Ssum (pass2 fused) + y_hat emit ----
__global__ __launch_bounds__(256) void k_scan(
    const unsigned int* __restrict__ G1, const float* __restrict__ G2,
    const float* __restrict__ Asum, const float* __restrict__ Ssum,
    const float* __restrict__ z0, unsigned short* __restrict__ yh)
{
  const int tid = threadIdx.x;
  const int n0 = tid*4;
  const int ch = blockIdx.x, b = blockIdx.y;
  float z[4];
  #pragma unroll
  for (int j = 0; j < 4; j++) z[j] = z0[b*N_ + n0 + j];
  for (int c2 = 0; c2 < ch; c2++){
    const size_t idx = (size_t)(b*NCH + c2)*N_ + n0;
    float4 Av = *(const float4*)(Asum + idx);
    float4 Sv = *(const float4*)(Ssum + idx);
    z[0] = fmaf(Av.x, z[0], Sv.x);
    z[1] = fmaf(Av.y, z[1], Sv.y);
    z[2] = fmaf(Av.z, z[2], Sv.z);
    z[3] = fmaf(Av.w, z[3], Sv.w);
  }
  const size_t base = (size_t)(b*T_ + ch*TC)*N_ + n0;
  const unsigned int* g1 = G1 + base;
  const float* g2 = G2 + base;
  unsigned short* Y = yh + base;
  #pragma unroll 4
  for (int i = 0; i < TC; i++){
    uint4 pac = *(const uint4*)g1;
    float4 bu = *(const float4*)g2;
    us4 ow;
    #pragma unroll
    for (int j = 0; j < 4; j++){
      unsigned int p = j==0 ? pac.x : j==1 ? pac.y : j==2 ? pac.z : pac.w;
      float buj     = j==0 ? bu.x  : j==1 ? bu.y  : j==2 ? bu.z  : bu.w;
      float a = bf2f((unsigned short)(p & 0xffffu));
      float c = bf2f((unsigned short)(p >> 16));
      float yv = c * z[j];
      z[j] = fmaf(a, z[j], buj);
      ow[j] = f2bf(yv);
    }
    *(us4*)Y = ow;
    g1 += N_; g2 += N_; Y += N_;
  }
}

extern "C" void kernel_launch(void* const* d_in, const int* in_sizes, int n_in,
                              void* d_out, int out_size, void* d_ws, size_t ws_size,
                              hipStream_t stream)
{
  const float* u    = (const float*)d_in[0];
  const float* z0   = (const float*)d_in[1];
  const float* Win  = (const float*)d_in[2];
  const float* Wout = (const float*)d_in[3];
  const float* pnw  = (const float*)d_in[4];
  const float* pnb  = (const float*)d_in[5];
  const float* alog = (const float*)d_in[6];
  const float* dbias= (const float*)d_in[7];
  const float* lgam = (const float*)d_in[8];

  char* ws = (char*)d_ws;
  size_t off = 0;
  auto alloc = [&](size_t bytes) -> void* {
    void* p = ws + off;
    off += (bytes + 255) & ~(size_t)255;
    return p;
  };
  float*          sc     = (float*)         alloc(1024);
  unsigned short* u16    = (unsigned short*)alloc((size_t)8192*1024*2);
  unsigned short* Wcat16 = (unsigned short*)alloc((size_t)4096*1024*2);
  unsigned short* Wout16 = (unsigned short*)alloc((size_t)1024*1024*2);
  unsigned int*   G1     = (unsigned int*)  alloc((size_t)8192*1024*4);
  float*          G2     = (float*)         alloc((size_t)8192*1024*4);
  unsigned short* yh16   = (unsigned short*)alloc((size_t)8192*1024*2);
  unsigned short* Hping  = (unsigned short*)alloc((size_t)2*1024*1024*2);
  unsigned short* Hpong  = (unsigned short*)alloc((size_t)2*1024*1024*2);
  float*          Asum   = (float*)alloc((size_t)B_*NCH*N_*4);
  float*          Ssum   = (float*)alloc((size_t)B_*NCH*N_*4);

  k_convert_all<<<CONV_BLOCKS, 256, 0, stream>>>(u, Win, pnw, Wout, u16, Wcat16, Wout16, sc);

  // spectral-norm chains: gram (step 0) + SQN squarings (triangular); frob fused in last step
  dim3 gsq(136, 1, 2);
  k_sq<<<gsq, 256, 0, stream>>>(Wcat16, Hping, Wout16, Hping + (size_t)1024*1024, sc, 0);
  unsigned short* hin = Hping;
  unsigned short* hout = Hpong;
  for (int s = 1; s <= SQN; s++){
    k_sq<<<gsq, 256, 0, stream>>>(hin, hout, hin + (size_t)1024*1024, hout + (size_t)1024*1024, sc, s);
    unsigned short* t = hin; hin = hout; hout = t;
  }

  // gated P-GEMM: gates + chunk (A,S) directly from the MFMA accumulators
  dim3 g1(4096/128, 8192/128);
  k_pgemm<<<g1, 256, 0, stream>>>(u16, Wcat16, alog, dbias, pnb, lgam, sc, G1, G2, Asum, Ssum);

  // fused pass2+pass3
  dim3 gsc(NCH, B_);
  k_scan<<<gsc, 256, 0, stream>>>(G1, G2, Asum, Ssum, z0, yh16);

  // y = (y_hat @ W_out^T) * inv_scale(sc,1)  (fp32 out)
  dim3 g2(1024/128, 8192/128);
  k_gemm<<<g2, 256, 0, stream>>>(yh16, Wout16, d_out == nullptr ? nullptr : (float*)d_out,
                                 8192, 1024, 1024, sc, 1);
}

// Round 11
// 278.627 us; speedup vs baseline: 4.3630x; 1.0420x over previous
//
#include <hip/hip_runtime.h>
#include <stdint.h>

#define B_ 4
#define T_ 2048
#define D_ 1024
#define N_ 1024
#define TC 16
#define NCH (T_/TC)
#define SQN 6   // squaring GEMMs after gram; +1 effective doubling via fused Frobenius

typedef __attribute__((ext_vector_type(4))) float f32x4;
typedef __attribute__((ext_vector_type(8))) short bf16x8;
typedef __attribute__((ext_vector_type(4))) unsigned short us4;

__device__ __forceinline__ unsigned short f2bf(float f){
  unsigned int u = __float_as_uint(f);
  return (unsigned short)((u + 0x7fffu + ((u >> 16) & 1u)) >> 16);
}
__device__ __forceinline__ float bf2f(unsigned short h){
  return __uint_as_float(((unsigned int)h) << 16);
}

// inverse spectral scale from trace chain (z=0: W_in, z=1: W_out)
__device__ __forceinline__ float inv_scale(const float* __restrict__ sc, int z){
  float ll = 0.f, w = 1.f, t = 1.f;
  #pragma unroll
  for (int i = 0; i <= SQN; i++){
    t = sc[8 + 2*i + z];
    ll += w * __logf(t);
    w *= 0.5f;
  }
  float F = sc[8 + 2*(SQN+1) + z];
  ll += w * __logf(F / (t*t));
  float sig = fmaxf(__expf(0.5f * ll), 1e-5f);
  return 1.f / fmaxf(sig, 1.f);
}

__device__ __forceinline__ float softplusf(float x){
  return (x > 0.f) ? (x + __logf(1.f + __expf(-x))) : __logf(1.f + __expf(x));
}
__device__ __forceinline__ float tanhfastf(float x){
  float e = __expf(2.f * x);
  return 1.f - 2.f/(e + 1.f);
}
__device__ __forceinline__ void abc_from(float pin, float draw, float braw, float craw,
    float alpha, float ginv, float& a_o, float& bu_o, float& c_o){
  float sp = softplusf(draw);
  float av = __expf(-sp * alpha);
  av = fminf(av, 1.f - 1e-4f);
  float bv = tanhfastf(braw);
  float cv = tanhfastf(craw);
  float p = av*av + cv*cv;
  float r = bv*bv;
  float q = av*bv;
  float pr = p - r;
  float disc = pr*pr + 4.f*q*q;
  float lam = 0.5f*(p + r + sqrtf(disc + 1e-12f));
  float inv = fminf(rsqrtf(lam + 1e-12f), 1.f);
  a_o = av * inv;
  c_o = cv * inv;
  bu_o = (bv * inv) * (pin * ginv);
}

// ---- fused fp32->bf16 conversion + INTERLEAVE of weight rows + sc zero-init ----
// Wcat16 row (4n+s): s=0 -> W_in[n], s=1..3 -> pn_w[(s-1)*N + n] (delta, b, c).
#define U4    2097152
#define WIN4   262144
#define PNW4   786432
#define WOUT4  262144
#define CONV_BLOCKS ((U4 + WIN4 + PNW4 + WOUT4 + 255)/256)

__global__ void k_convert_all(const float* __restrict__ u, const float* __restrict__ Win,
                              const float* __restrict__ pnw, const float* __restrict__ Wout,
                              unsigned short* __restrict__ u16, unsigned short* __restrict__ Wcat16,
                              unsigned short* __restrict__ Wout16, float* __restrict__ sc){
  if (blockIdx.x == 0 && threadIdx.x < 64) sc[threadIdx.x] = 0.f;
  long i = (long)blockIdx.x * 256 + threadIdx.x;
  const float* src; long o; size_t didx; unsigned short* dbuf;
  if (i < U4){
    src = u; o = i; dbuf = u16; didx = (size_t)o;
  } else if (i < U4+WIN4){
    o = i - U4; src = Win;
    int n = (int)(o >> 8), c4 = (int)(o & 255);
    dbuf = Wcat16; didx = (size_t)(4*n)*256 + c4;
  } else if (i < U4+WIN4+PNW4){
    o = i - (U4+WIN4); src = pnw;
    int m = (int)(o >> 8), c4 = (int)(o & 255);
    int s = (m >> 10) + 1, n = m & 1023;
    dbuf = Wcat16; didx = (size_t)(4*n + s)*256 + c4;
  } else if (i < U4+WIN4+PNW4+WOUT4){
    o = i - (U4+WIN4+PNW4); src = Wout; dbuf = Wout16; didx = (size_t)o;
  } else return;
  float4 v = ((const float4*)src)[o];
  us4 w;
  w.x = f2bf(v.x); w.y = f2bf(v.y); w.z = f2bf(v.z); w.w = f2bf(v.w);
  ((us4*)dbuf)[didx] = w;
}

__device__ __forceinline__ void load_lds16(const unsigned short* g, unsigned short* l){
  __builtin_amdgcn_global_load_lds((const __attribute__((address_space(1))) void*)g,
                                   (__attribute__((address_space(3))) void*)l, 16, 0, 0);
}

// ==== gated P-GEMM: u @ Wcat^T in 128x128 tiles; epilogue transposes acc via an
// LDS slab (staging buffer reused) so each lane owns ONE n with all 4 gate
// streams per row: gates in fp32, G1/G2 stores, chunk (A,S) via 3 in-lane fma +
// 2-step butterfly. P never materialized; pass1/pass2 eliminated.
__global__ __launch_bounds__(256) void k_pgemm(
    const unsigned short* __restrict__ A,
    const unsigned short* __restrict__ Bmat,
    const float* __restrict__ alog, const float* __restrict__ dbias,
    const float* __restrict__ pnb, const float* __restrict__ lgam,
    const float* __restrict__ sc,
    unsigned int* __restrict__ G1,   // [t][n] packed (a, c) bf16
    float* __restrict__ G2,          // [t][n] bu fp32
    float* __restrict__ Asum, float* __restrict__ Ssum)
{
  __shared__ alignas(16) unsigned char smem[32768];
  unsigned short* As = (unsigned short*)smem;
  unsigned short* Bs = (unsigned short*)(smem + 16384);
  const int tid = threadIdx.x;
  const int wid = tid >> 6;
  const int lane = tid & 63;
  const int bn = blockIdx.x, bm = blockIdx.y;
  const int K = 1024;

  const int wr = wid >> 1, wc = wid & 1;
  const int rg = lane >> 3;
  const int cby = (lane & 7) << 4;
  const int srow0 = wid * 32;
  const int frow = lane & 15;
  const int kgrp = lane >> 4;

  const unsigned short* ap[4];
  const unsigned short* bp[4];
  unsigned short* adst[4];
  unsigned short* bdst[4];
  #pragma unroll
  for (int i = 0; i < 4; i++){
    int r = srow0 + i*8 + rg;
    int cb = cby ^ ((r & 7) << 4);
    ap[i] = A    + (size_t)(bm*128 + r)*K + (cb >> 1);
    bp[i] = Bmat + (size_t)(bn*128 + r)*K + (cb >> 1);
    adst[i] = As + (srow0 + i*8)*64;
    bdst[i] = Bs + (srow0 + i*8)*64;
  }
  int aoff[4][2], boff[4][2];
  #pragma unroll
  for (int m = 0; m < 4; m++){
    int r = wr*64 + m*16 + frow;
    #pragma unroll
    for (int kk = 0; kk < 2; kk++)
      aoff[m][kk] = r*128 + ((kk*64 + kgrp*16) ^ ((r & 7) << 4));
  }
  #pragma unroll
  for (int n2 = 0; n2 < 4; n2++){
    int r = wc*64 + n2*16 + frow;
    #pragma unroll
    for (int kk = 0; kk < 2; kk++)
      boff[n2][kk] = r*128 + ((kk*64 + kgrp*16) ^ ((r & 7) << 4));
  }

  f32x4 acc[4][4] = {};

  for (int kt = 0; kt < K; kt += 64){
    #pragma unroll
    for (int i = 0; i < 4; i++){
      load_lds16(ap[i], adst[i]);
      load_lds16(bp[i], bdst[i]);
      ap[i] += 64; bp[i] += 64;
    }
    __syncthreads();
    #pragma unroll
    for (int kk = 0; kk < 2; kk++){
      bf16x8 af[4], bfv[4];
      #pragma unroll
      for (int m = 0; m < 4; m++)
        af[m] = *(const bf16x8*)((const char*)As + aoff[m][kk]);
      #pragma unroll
      for (int n2 = 0; n2 < 4; n2++)
        bfv[n2] = *(const bf16x8*)((const char*)Bs + boff[n2][kk]);
      #pragma unroll
      for (int m = 0; m < 4; m++)
        #pragma unroll
        for (int n2 = 0; n2 < 4; n2++)
          acc[m][n2] = __builtin_amdgcn_mfma_f32_16x16x32_bf16(af[m], bfv[n2], acc[m][n2], 0, 0, 0);
    }
    __syncthreads();
  }

  // ===== gated epilogue v2: LDS-slab transpose (per-wave region, no barriers) =====
  const int nl = lane & 15;                 // read-side local n
  const int tg = lane >> 4;                 // read-side t-group (== kgrp bits)
  const float ginv = __expf(lgam[0]) * inv_scale(sc, 0);
  const int ng = bn*32 + wc*16 + nl;        // global n for this lane
  const float alpha = softplusf(alog[ng]);
  const float bd = dbias[ng] + pnb[ng];
  const float bb = pnb[N_ + ng];
  const float bc = pnb[2*N_ + ng];

  float* slab = (float*)smem + wid*1088;    // 16 rows x 68-float pitch (4352 B/wave)
  const int wbase = kgrp*4*68 + frow;       // + j*68 + n2*16
  const int rbase = tg*4*68 + nl*4;         // + j*68

  #pragma unroll
  for (int m = 0; m < 4; m++){
    __builtin_amdgcn_sched_barrier(0);      // keep m-slab write/read phases ordered
    #pragma unroll
    for (int n2 = 0; n2 < 4; n2++)
      #pragma unroll
      for (int j = 0; j < 4; j++)
        slab[wbase + j*68 + n2*16] = acc[m][n2][j];
    asm volatile("s_waitcnt lgkmcnt(0)" ::: "memory");
    __builtin_amdgcn_sched_barrier(0);
    float Ar = 1.f, Sr = 0.f;
    #pragma unroll
    for (int j = 0; j < 4; j++){
      f32x4 v = *(const f32x4*)(slab + rbase + j*68);
      float a, bu, c;
      abc_from(v[0], v[1] + bd, v[2] + bb, v[3] + bc, alpha, ginv, a, bu, c);
      const int row = bm*128 + wr*64 + m*16 + tg*4 + j;
      G1[(size_t)row*N_ + ng] = (unsigned int)f2bf(a) | ((unsigned int)f2bf(c) << 16);
      G2[(size_t)row*N_ + ng] = bu;
      Sr = fmaf(a, Sr, bu);                 // ordered: t ascending within lane
      Ar *= a;
    }
    // cross-lane over t-groups, LSB-first (bit4 then bit5)
    { float Ap = __shfl_xor(Ar,16,64), Sp = __shfl_xor(Sr,16,64);
      if (lane & 16){ Sr = fmaf(Ar, Sp, Sr); } else { Sr = fmaf(Ap, Sr, Sp); } Ar *= Ap; }
    { float Ap = __shfl_xor(Ar,32,64), Sp = __shfl_xor(Sr,32,64);
      if (lane & 32){ Sr = fmaf(Ar, Sp, Sr); } else { Sr = fmaf(Ap, Sr, Sp); } Ar *= Ap; }
    if (tg == 0){
      const int chunk = bm*8 + wr*4 + m;    // global row / 16
      Asum[(size_t)chunk*N_ + ng] = Ar;
      Ssum[(size_t)chunk*N_ + ng] = Sr;
    }
  }
}

// ---- out-GEMM: C[M,N] = (A[M,K] * B[N,K]^T) * inv_scale(step)  (128x128, m97) ----
__global__ __launch_bounds__(256) void k_gemm(
    const unsigned short* __restrict__ A,
    const unsigned short* __restrict__ Bmat,
    float* __restrict__ C,
    int M, int N, int K,
    const float* __restrict__ sc, int step)
{
  __shared__ alignas(16) unsigned short As[128*64];
  __shared__ alignas(16) unsigned short Bs[128*64];
  const int tid = threadIdx.x;
  const int wid = tid >> 6;
  const int lane = tid & 63;
  const int bn = blockIdx.x, bm = blockIdx.y;

  float outscale = (step >= 0) ? inv_scale(sc, step) : 1.f;

  const int wr = wid >> 1, wc = wid & 1;
  const int rg = lane >> 3;
  const int cby = (lane & 7) << 4;
  const int srow0 = wid * 32;
  const int frow = lane & 15;
  const int kgrp = lane >> 4;

  const unsigned short* ap[4];
  const unsigned short* bp[4];
  unsigned short* adst[4];
  unsigned short* bdst[4];
  #pragma unroll
  for (int i = 0; i < 4; i++){
    int r = srow0 + i*8 + rg;
    int cb = cby ^ ((r & 7) << 4);
    ap[i] = A    + (size_t)(bm*128 + r)*K + (cb >> 1);
    bp[i] = Bmat + (size_t)(bn*128 + r)*K + (cb >> 1);
    adst[i] = As + (srow0 + i*8)*64;
    bdst[i] = Bs + (srow0 + i*8)*64;
  }
  int aoff[4][2], boff[4][2];
  #pragma unroll
  for (int m = 0; m < 4; m++){
    int r = wr*64 + m*16 + frow;
    #pragma unroll
    for (int kk = 0; kk < 2; kk++)
      aoff[m][kk] = r*128 + ((kk*64 + kgrp*16) ^ ((r & 7) << 4));
  }
  #pragma unroll
  for (int n2 = 0; n2 < 4; n2++){
    int r = wc*64 + n2*16 + frow;
    #pragma unroll
    for (int kk = 0; kk < 2; kk++)
      boff[n2][kk] = r*128 + ((kk*64 + kgrp*16) ^ ((r & 7) << 4));
  }

  f32x4 acc[4][4] = {};

  for (int kt = 0; kt < K; kt += 64){
    #pragma unroll
    for (int i = 0; i < 4; i++){
      load_lds16(ap[i], adst[i]);
      load_lds16(bp[i], bdst[i]);
      ap[i] += 64; bp[i] += 64;
    }
    __syncthreads();
    #pragma unroll
    for (int kk = 0; kk < 2; kk++){
      bf16x8 af[4], bfv[4];
      #pragma unroll
      for (int m = 0; m < 4; m++)
        af[m] = *(const bf16x8*)((const char*)As + aoff[m][kk]);
      #pragma unroll
      for (int n2 = 0; n2 < 4; n2++)
        bfv[n2] = *(const bf16x8*)((const char*)Bs + boff[n2][kk]);
      #pragma unroll
      for (int m = 0; m < 4; m++)
        #pragma unroll
        for (int n2 = 0; n2 < 4; n2++)
          acc[m][n2] = __builtin_amdgcn_mfma_f32_16x16x32_bf16(af[m], bfv[n2], acc[m][n2], 0, 0, 0);
    }
    __syncthreads();
  }

  const int row0 = bm*128 + wr*64;
  const int col0 = bn*128 + wc*64 + frow;
  #pragma unroll
  for (int m = 0; m < 4; m++){
    #pragma unroll
    for (int n2 = 0; n2 < 4; n2++){
      const int col = col0 + n2*16;
      const int rb = row0 + m*16 + kgrp*4;
      #pragma unroll
      for (int j = 0; j < 4; j++)
        C[(size_t)(rb + j)*N + col] = acc[m][n2][j] * outscale;
    }
  }
}

// ---- triangular squaring-chain GEMM (C = X*X^T symmetric, upper tiles only) ----
__global__ __launch_bounds__(256) void k_sq(
    const unsigned short* __restrict__ A0, unsigned short* __restrict__ C0,
    const unsigned short* __restrict__ A1, unsigned short* __restrict__ C1,
    float* __restrict__ sc, int step)
{
  __shared__ alignas(16) unsigned short As0[64*128], Bs0[64*128];
  __shared__ alignas(16) unsigned short As1[64*128], Bs1[64*128];
  const int tid = threadIdx.x;
  const int wid = tid >> 6;
  const int lane = tid & 63;
  const int z = blockIdx.z;

  int x = blockIdx.x, bm = 0;
  while (x >= 16 - bm){ x -= 16 - bm; bm++; }
  const int bn = bm + x;

  const unsigned short* A = z ? A1 : A0;
  unsigned short* C = z ? C1 : C0;
  const size_t rs = (step == 0 && z == 0) ? 4096 : 1024;
  float outscale = 1.f;
  if (step > 0){ float t = sc[8 + (step-1)*2 + z]; outscale = 1.f/(t*t); }

  const int wr = wid >> 1, wc = wid & 1;
  const int frow = lane & 15;
  const int kgrp = lane >> 4;

  const int srl = lane >> 4;
  const int sgr = lane & 15;
  const int swzr = wid*4 + srl;
  const int scol_e = ((sgr ^ swzr) << 3);

  const size_t Arow = (size_t)bm * 64;
  const size_t Brow = (size_t)bn * 64;

  f32x4 acc[2][2] = {};

  auto stage = [&](unsigned short* as, unsigned short* bs, int t){
    const int kt = t * 128;
    #pragma unroll
    for (int i = 0; i < 4; i++){
      int r = i*16 + wid*4 + srl;
      load_lds16(A + (Arow + r)*rs + kt + scol_e, as + (i*16 + wid*4)*128);
      load_lds16(A + (Brow + r)*rs + kt + scol_e, bs + (i*16 + wid*4)*128);
    }
  };

  auto compute = [&](const unsigned short* as, const unsigned short* bs){
    #pragma unroll
    for (int ks = 0; ks < 4; ks++){
      const int kb = ks*64 + kgrp*16;
      bf16x8 af[2], bfv[2];
      #pragma unroll
      for (int m = 0; m < 2; m++){
        int r = wr*32 + m*16 + frow;
        af[m] = *(const bf16x8*)((const char*)as + r*256 + (kb ^ (frow << 4)));
      }
      #pragma unroll
      for (int n2 = 0; n2 < 2; n2++){
        int r = wc*32 + n2*16 + frow;
        bfv[n2] = *(const bf16x8*)((const char*)bs + r*256 + (kb ^ (frow << 4)));
      }
      #pragma unroll
      for (int m = 0; m < 2; m++)
        #pragma unroll
        for (int n2 = 0; n2 < 2; n2++)
          acc[m][n2] = __builtin_amdgcn_mfma_f32_16x16x32_bf16(af[m], bfv[n2], acc[m][n2], 0, 0, 0);
    }
  };

  stage(As0, Bs0, 0);
  __syncthreads();
  for (int t2 = 0; t2 < 8; t2 += 2){
    if (t2 + 1 < 8) stage(As1, Bs1, t2 + 1);
    compute(As0, Bs0);
    __syncthreads();
    if (t2 + 2 < 8) stage(As0, Bs0, t2 + 2);
    compute(As1, Bs1);
    __syncthreads();
  }

  const int row0 = bm*64 + wr*32;
  const int col0 = bn*64 + wc*32 + frow;
  float fr = 0.f;
  #pragma unroll
  for (int m = 0; m < 2; m++){
    #pragma unroll
    for (int n2 = 0; n2 < 2; n2++){
      const int col = col0 + n2*16;
      const int rb = row0 + m*16 + kgrp*4;
      us4 tw;
      #pragma unroll
      for (int j = 0; j < 4; j++){
        float v = acc[m][n2][j] * outscale;
        unsigned short h = f2bf(v);
        C[(size_t)(rb + j)*1024 + col] = h;
        tw[j] = h;
        fr += v*v;
      }
      if (bm != bn)
        *(us4*)(C + (size_t)col*1024 + rb) = tw;
    }
  }
  if (bm == bn && wr == wc){
    int j = frow - kgrp*4;
    if (j >= 0 && j < 4){
      float d = (acc[0][0][j] + acc[1][1][j]) * outscale;
      atomicAdd(&sc[8 + step*2 + z], d);
    }
  }
  if (step == SQN){
    if (bm != bn) fr *= 2.f;
    #pragma unroll
    for (int off = 32; off; off >>= 1) fr += __shfl_down(fr, off, 64);
    if (lane == 0) atomicAdd(&sc[8 + 2*(SQN+1) + z], fr);
  }
}

// ---- k_scan: self prefix-scan over Asum/Ssum (pass2 fused) + y_hat emit ----
__global__ __launch_bounds__(256) void k_scan(
    const unsigned int* __restrict__ G1, const float* __restrict__ G2,
    const float* __restrict__ Asum, const float* __restrict__ Ssum,
    const float* __restrict__ z0, unsigned short* __restrict__ yh)
{
  const int tid = threadIdx.x;
  const int n0 = tid*4;
  const int ch = blockIdx.x, b = blockIdx.y;
  float z[4];
  #pragma unroll
  for (int j = 0; j < 4; j++) z[j] = z0[b*N_ + n0 + j];
  for (int c2 = 0; c2 < ch; c2++){
    const size_t idx = (size_t)(b*NCH + c2)*N_ + n0;
    float4 Av = *(const float4*)(Asum + idx);
    float4 Sv = *(const float4*)(Ssum + idx);
    z[0] = fmaf(Av.x, z[0], Sv.x);
    z[1] = fmaf(Av.y, z[1], Sv.y);
    z[2] = fmaf(Av.z, z[2], Sv.z);
    z[3] = fmaf(Av.w, z[3], Sv.w);
  }
  const size_t base = (size_t)(b*T_ + ch*TC)*N_ + n0;
  const unsigned int* g1 = G1 + base;
  const float* g2 = G2 + base;
  unsigned short* Y = yh + base;
  #pragma unroll 4
  for (int i = 0; i < TC; i++){
    uint4 pac = *(const uint4*)g1;
    float4 bu = *(const float4*)g2;
    us4 ow;
    #pragma unroll
    for (int j = 0; j < 4; j++){
      unsigned int p = j==0 ? pac.x : j==1 ? pac.y : j==2 ? pac.z : pac.w;
      float buj     = j==0 ? bu.x  : j==1 ? bu.y  : j==2 ? bu.z  : bu.w;
      float a = bf2f((unsigned short)(p & 0xffffu));
      float c = bf2f((unsigned short)(p >> 16));
      float yv = c * z[j];
      z[j] = fmaf(a, z[j], buj);
      ow[j] = f2bf(yv);
    }
    *(us4*)Y = ow;
    g1 += N_; g2 += N_; Y += N_;
  }
}

extern "C" void kernel_launch(void* const* d_in, const int* in_sizes, int n_in,
                              void* d_out, int out_size, void* d_ws, size_t ws_size,
                              hipStream_t stream)
{
  const float* u    = (const float*)d_in[0];
  const float* z0   = (const float*)d_in[1];
  const float* Win  = (const float*)d_in[2];
  const float* Wout = (const float*)d_in[3];
  const float* pnw  = (const float*)d_in[4];
  const float* pnb  = (const float*)d_in[5];
  const float* alog = (const float*)d_in[6];
  const float* dbias= (const float*)d_in[7];
  const float* lgam = (const float*)d_in[8];

  char* ws = (char*)d_ws;
  size_t off = 0;
  auto alloc = [&](size_t bytes) -> void* {
    void* p = ws + off;
    off += (bytes + 255) & ~(size_t)255;
    return p;
  };
  float*          sc     = (float*)         alloc(1024);
  unsigned short* u16    = (unsigned short*)alloc((size_t)8192*1024*2);
  unsigned short* Wcat16 = (unsigned short*)alloc((size_t)4096*1024*2);
  unsigned short* Wout16 = (unsigned short*)alloc((size_t)1024*1024*2);
  unsigned int*   G1     = (unsigned int*)  alloc((size_t)8192*1024*4);
  float*          G2     = (float*)         alloc((size_t)8192*1024*4);
  unsigned short* yh16   = (unsigned short*)alloc((size_t)8192*1024*2);
  unsigned short* Hping  = (unsigned short*)alloc((size_t)2*1024*1024*2);
  unsigned short* Hpong  = (unsigned short*)alloc((size_t)2*1024*1024*2);
  float*          Asum   = (float*)alloc((size_t)B_*NCH*N_*4);
  float*          Ssum   = (float*)alloc((size_t)B_*NCH*N_*4);

  k_convert_all<<<CONV_BLOCKS, 256, 0, stream>>>(u, Win, pnw, Wout, u16, Wcat16, Wout16, sc);

  // spectral-norm chains: gram (step 0) + SQN squarings (triangular); frob fused in last step
  dim3 gsq(136, 1, 2);
  k_sq<<<gsq, 256, 0, stream>>>(Wcat16, Hping, Wout16, Hping + (size_t)1024*1024, sc, 0);
  unsigned short* hin = Hping;
  unsigned short* hout = Hpong;
  for (int s = 1; s <= SQN; s++){
    k_sq<<<gsq, 256, 0, stream>>>(hin, hout, hin + (size_t)1024*1024, hout + (size_t)1024*1024, sc, s);
    unsigned short* t = hin; hin = hout; hout = t;
  }

  // gated P-GEMM: gates + chunk (A,S) directly from the MFMA accumulators
  dim3 g1(4096/128, 8192/128);
  k_pgemm<<<g1, 256, 0, stream>>>(u16, Wcat16, alog, dbias, pnb, lgam, sc, G1, G2, Asum, Ssum);

  // fused pass2+pass3
  dim3 gsc(NCH, B_);
  k_scan<<<gsc, 256, 0, stream>>>(G1, G2, Asum, Ssum, z0, yh16);

  // y = (y_hat @ W_out^T) * inv_scale(sc,1)  (fp32 out)
  dim3 g2(1024/128, 8192/128);
  k_gemm<<<g2, 256, 0, stream>>>(yh16, Wout16, (float*)d_out, 8192, 1024, 1024, sc, 1);
}